// Round 1
// baseline (5713.260 us; speedup 1.0000x reference)
//
#include <hip/hip_runtime.h>
#include <hip/hip_bf16.h>

#define NN 100000      // nodes
#define NE 1600000     // edges
#define NB 128         // graphs
#define NV 10000       // vocab
#define HD 128         // emb = hid = 128

// ---------------- degree / norm ----------------
__global__ void k_init_deg(float* deg) {
  int i = blockIdx.x * blockDim.x + threadIdx.x;
  if (i < NN) deg[i] = 1.0f;            // self-loop weight 1
}

__global__ void k_deg(const int* __restrict__ dst, const float* __restrict__ ew,
                      float* __restrict__ deg) {
  int e = blockIdx.x * blockDim.x + threadIdx.x;
  if (e < NE) atomicAdd(&deg[dst[e]], ew[e]);
}

__global__ void k_dinv(float* deg) {
  int i = blockIdx.x * blockDim.x + threadIdx.x;
  if (i < NN) deg[i] = rsqrtf(deg[i]);  // deg >= 1 always
}

__global__ void k_norm(const int* __restrict__ src, const int* __restrict__ dst,
                       const float* __restrict__ ew, const float* __restrict__ dinv,
                       float* __restrict__ norm) {
  int e = blockIdx.x * blockDim.x + threadIdx.x;
  if (e < NE) norm[e] = dinv[src[e]] * ew[e] * dinv[dst[e]];
}

// ---------------- GEMM: C[M,128] = A[M,128] @ W[128,128] ----------------
// block = 256 threads, tile = 128 rows. LDS: As[128][132] (padded) + Ws[128][128].
// thread (rg = t>>3 in 0..31, cg = t&7): rows {rg+32i}, cols {cg*4+32q}.
// Both LDS read patterns are bank-conflict-free (row stride 132 -> bank step 4).
__global__ __launch_bounds__(256) void k_gemm128(const float* __restrict__ A,
                                                 const float* __restrict__ W,
                                                 float* __restrict__ C, int M) {
  __shared__ float As[128][132];
  __shared__ float Ws[128][128];
  const int t = threadIdx.x;
  const int row0 = blockIdx.x * 128;

  const float4* W4 = reinterpret_cast<const float4*>(W);
  for (int i = t; i < 4096; i += 256) {
    float4 v = W4[i];
    int fi = i * 4; int r = fi >> 7; int c = fi & 127;
    *reinterpret_cast<float4*>(&Ws[r][c]) = v;
  }
  const float4* A4 = reinterpret_cast<const float4*>(A);
  for (int i = t; i < 4096; i += 256) {
    int fi = i * 4; int r = fi >> 7; int c = fi & 127;
    float4 v = make_float4(0.f, 0.f, 0.f, 0.f);
    if (row0 + r < M) v = A4[((size_t)(row0 + r) * HD + c) >> 2];
    *reinterpret_cast<float4*>(&As[r][c]) = v;
  }
  __syncthreads();

  const int rg = t >> 3;   // 0..31
  const int cg = t & 7;    // 0..7
  float acc[4][16];
  #pragma unroll
  for (int i = 0; i < 4; ++i)
    #pragma unroll
    for (int j = 0; j < 16; ++j) acc[i][j] = 0.f;

  for (int k = 0; k < 128; ++k) {
    float a[4];
    #pragma unroll
    for (int i = 0; i < 4; ++i) a[i] = As[32 * i + rg][k];
    #pragma unroll
    for (int q = 0; q < 4; ++q) {
      float4 w = *reinterpret_cast<const float4*>(&Ws[k][cg * 4 + 32 * q]);
      #pragma unroll
      for (int i = 0; i < 4; ++i) {
        acc[i][q * 4 + 0] += a[i] * w.x;
        acc[i][q * 4 + 1] += a[i] * w.y;
        acc[i][q * 4 + 2] += a[i] * w.z;
        acc[i][q * 4 + 3] += a[i] * w.w;
      }
    }
  }

  #pragma unroll
  for (int i = 0; i < 4; ++i) {
    int row = row0 + 32 * i + rg;
    if (row < M) {
      #pragma unroll
      for (int q = 0; q < 4; ++q) {
        float4 v = make_float4(acc[i][q * 4 + 0], acc[i][q * 4 + 1],
                               acc[i][q * 4 + 2], acc[i][q * 4 + 3]);
        *reinterpret_cast<float4*>(&C[(size_t)row * HD + cg * 4 + 32 * q]) = v;
      }
    }
  }
}

// ---------------- self-loop init: out[n] = xw[n or xidx[n]] * dinv[n]^2 ----------------
template <bool IND>
__global__ void k_self(const float* __restrict__ xw, const int* __restrict__ xidx,
                       const float* __restrict__ dinv, float* __restrict__ out) {
  int tid = blockIdx.x * blockDim.x + threadIdx.x;
  int n = tid >> 5, lane = tid & 31;
  if (n >= NN) return;
  int s = IND ? xidx[n] : n;
  float d = dinv[n];
  float c = d * d;
  float4 v = reinterpret_cast<const float4*>(xw + (size_t)s * HD)[lane];
  float4 r = make_float4(v.x * c, v.y * c, v.z * c, v.w * c);
  reinterpret_cast<float4*>(out + (size_t)n * HD)[lane] = r;
}

// ---------------- edge scatter: out[dst] += norm * xw[src (or xidx[src])] ----------------
template <bool IND>
__global__ void k_scatter(const float* __restrict__ xw, const int* __restrict__ xidx,
                          const int* __restrict__ src, const int* __restrict__ dst,
                          const float* __restrict__ norm, float* __restrict__ out) {
  int tid = blockIdx.x * blockDim.x + threadIdx.x;
  int e = tid >> 5, lane = tid & 31;
  if (e >= NE) return;
  int s = src[e];
  int d = dst[e];
  if (IND) s = xidx[s];
  float c = norm[e];
  float4 v = reinterpret_cast<const float4*>(xw + (size_t)s * HD)[lane];
  float* o = out + (size_t)d * HD + lane * 4;
  atomicAdd(o + 0, v.x * c);
  atomicAdd(o + 1, v.y * c);
  atomicAdd(o + 2, v.z * c);
  atomicAdd(o + 3, v.w * c);
}

// ---------------- relu(x + b) in place ----------------
__global__ void k_relu_bias(float* __restrict__ x, const float* __restrict__ b) {
  int i = blockIdx.x * blockDim.x + threadIdx.x;
  if (i >= NN * HD / 4) return;
  float4 v = reinterpret_cast<float4*>(x)[i];
  int c = (i * 4) & (HD - 1);
  float4 bb = *reinterpret_cast<const float4*>(b + c);
  v.x = fmaxf(v.x + bb.x, 0.f);
  v.y = fmaxf(v.y + bb.y, 0.f);
  v.z = fmaxf(v.z + bb.z, 0.f);
  v.w = fmaxf(v.w + bb.w, 0.f);
  reinterpret_cast<float4*>(x)[i] = v;
}

// ---------------- pooling ----------------
__global__ void k_zero(float* p, int n) {
  int i = blockIdx.x * blockDim.x + threadIdx.x;
  if (i < n) p[i] = 0.f;
}

// 32 lanes per 8-node run; batch is sorted so runs collapse most atomics.
__global__ void k_pool(const float* __restrict__ x, const int* __restrict__ batch,
                       float* __restrict__ sums) {
  int tid = blockIdx.x * blockDim.x + threadIdx.x;
  int g = tid >> 5, lane = tid & 31;
  int n0 = g * 8;
  if (n0 >= NN) return;
  int nend = min(n0 + 8, NN);
  float4 acc = make_float4(0.f, 0.f, 0.f, 0.f);
  int curb = batch[n0];
  for (int n = n0; n < nend; ++n) {
    int b = batch[n];
    if (b != curb) {
      float* o = sums + (size_t)curb * HD + lane * 4;
      atomicAdd(o + 0, acc.x); atomicAdd(o + 1, acc.y);
      atomicAdd(o + 2, acc.z); atomicAdd(o + 3, acc.w);
      acc = make_float4(0.f, 0.f, 0.f, 0.f);
      curb = b;
    }
    float4 v = reinterpret_cast<const float4*>(x + (size_t)n * HD)[lane];
    acc.x += v.x; acc.y += v.y; acc.z += v.z; acc.w += v.w;
  }
  float* o = sums + (size_t)curb * HD + lane * 4;
  atomicAdd(o + 0, acc.x); atomicAdd(o + 1, acc.y);
  atomicAdd(o + 2, acc.z); atomicAdd(o + 3, acc.w);
}

// counts via binary search on sorted batch (no atomics)
__global__ void k_counts(const int* __restrict__ batch, float* __restrict__ cnt) {
  int b = threadIdx.x;
  if (b >= NB) return;
  auto lb = [&](int v) {
    int lo = 0, hi = NN;
    while (lo < hi) { int m = (lo + hi) >> 1; if (batch[m] < v) lo = m + 1; else hi = m; }
    return lo;
  };
  cnt[b] = (float)(lb(b + 1) - lb(b));
}

// ---------------- MLP head + softmax ----------------
__global__ __launch_bounds__(64) void k_head(const float* __restrict__ sums,
                                             const float* __restrict__ cnt,
                                             const float* __restrict__ W1,
                                             const float* __restrict__ b1,
                                             const float* __restrict__ W2,
                                             const float* __restrict__ b2,
                                             float* __restrict__ out) {
  int g = blockIdx.x, t = threadIdx.x;  // 64 threads
  __shared__ float gv[128];
  __shared__ float h[64];
  __shared__ float logits[2];
  float c = fmaxf(cnt[g], 1.0f);
  gv[t] = sums[g * HD + t] / c;
  gv[t + 64] = sums[g * HD + 64 + t] / c;
  __syncthreads();
  float acc = b1[t];
  for (int k = 0; k < 128; ++k) acc += gv[k] * W1[k * 64 + t];
  h[t] = fmaxf(acc, 0.f);
  __syncthreads();
  if (t < 2) {
    float a = b2[t];
    for (int j = 0; j < 64; ++j) a += h[j] * W2[j * 2 + t];
    logits[t] = a;
  }
  __syncthreads();
  if (t < 2) {
    float m = fmaxf(logits[0], logits[1]);
    float e0 = __expf(logits[0] - m), e1 = __expf(logits[1] - m);
    out[g * 2 + t] = (t == 0 ? e0 : e1) / (e0 + e1);
  }
}

// ---------------- launch ----------------
extern "C" void kernel_launch(void* const* d_in, const int* in_sizes, int n_in,
                              void* d_out, int out_size, void* d_ws, size_t ws_size,
                              hipStream_t stream) {
  const int*   x_idx = (const int*)d_in[0];
  const int*   eidx  = (const int*)d_in[1];
  const float* ew    = (const float*)d_in[2];
  const int*   batch = (const int*)d_in[3];
  const float* emb   = (const float*)d_in[4];
  const float* W1    = (const float*)d_in[5];
  const float* b1    = (const float*)d_in[6];
  const float* W2    = (const float*)d_in[7];
  const float* b2    = (const float*)d_in[8];
  const float* mW1   = (const float*)d_in[9];
  const float* mb1   = (const float*)d_in[10];
  const float* mW2   = (const float*)d_in[11];
  const float* mb2   = (const float*)d_in[12];
  const int* src = eidx;
  const int* dst = eidx + NE;
  float* out = (float*)d_out;

  char* ws = (char*)d_ws;
  size_t off = 0;
  auto alloc = [&](size_t bytes) {
    void* p = ws + off;
    off += (bytes + 255) & ~(size_t)255;
    return p;
  };
  float* dinv = (float*)alloc((size_t)NN * 4);
  float* norm = (float*)alloc((size_t)NE * 4);
  float* embW = (float*)alloc((size_t)NV * HD * 4);
  float* bufA = (float*)alloc((size_t)NN * HD * 4);
  float* bufB = (float*)alloc((size_t)NN * HD * 4);
  float* sums = (float*)alloc((size_t)NB * HD * 4);
  float* cnt  = (float*)alloc((size_t)NB * 4);

  // degree / norm
  k_init_deg<<<(NN + 255) / 256, 256, 0, stream>>>(dinv);
  k_deg<<<(NE + 255) / 256, 256, 0, stream>>>(dst, ew, dinv);
  k_dinv<<<(NN + 255) / 256, 256, 0, stream>>>(dinv);
  k_norm<<<(NE + 255) / 256, 256, 0, stream>>>(src, dst, ew, dinv, norm);

  // embW = emb_table @ W1  (so conv1's xW is a gather of embW)
  k_gemm128<<<(NV + 127) / 128, 256, 0, stream>>>(emb, W1, embW, NV);

  // conv1: bufB = aggregate(embW[x_idx]) ; relu(+b1)
  k_self<true><<<(NN * 32 + 255) / 256, 256, 0, stream>>>(embW, x_idx, dinv, bufB);
  k_scatter<true><<<(int)(((size_t)NE * 32 + 255) / 256), 256, 0, stream>>>(
      embW, x_idx, src, dst, norm, bufB);
  k_relu_bias<<<(NN * HD / 4 + 255) / 256, 256, 0, stream>>>(bufB, b1);

  // conv2: bufA = h1 @ W2 ; bufB = aggregate(bufA) ; relu(+b2)
  k_gemm128<<<(NN + 127) / 128, 256, 0, stream>>>(bufB, W2, bufA, NN);
  k_self<false><<<(NN * 32 + 255) / 256, 256, 0, stream>>>(bufA, nullptr, dinv, bufB);
  k_scatter<false><<<(int)(((size_t)NE * 32 + 255) / 256), 256, 0, stream>>>(
      bufA, nullptr, src, dst, norm, bufB);
  k_relu_bias<<<(NN * HD / 4 + 255) / 256, 256, 0, stream>>>(bufB, b2);

  // pool + head
  k_zero<<<(NB * HD + 255) / 256, 256, 0, stream>>>(sums, NB * HD);
  k_pool<<<((NN + 7) / 8 * 32 + 255) / 256, 256, 0, stream>>>(bufB, batch, sums);
  k_counts<<<1, 128, 0, stream>>>(batch, cnt);
  k_head<<<NB, 64, 0, stream>>>(sums, cnt, mW1, mb1, mW2, mb2, out);
}

// Round 2
// 682.190 us; speedup vs baseline: 8.3749x; 8.3749x over previous
//
#include <hip/hip_runtime.h>
#include <hip/hip_bf16.h>

#define NN 100000      // nodes
#define NE 1600000     // edges
#define NB 128         // graphs
#define NV 10000       // vocab
#define HD 128         // emb = hid = 128
#define NBLK 196       // ceil(NN/512) for scan

// ---------------- degree(+selfloop) / in-degree histogram ----------------
__global__ void k_init(float* deg, int* hist) {
  int i = blockIdx.x * blockDim.x + threadIdx.x;
  if (i < NN) { deg[i] = 1.0f; hist[i] = 0; }
}

__global__ void k_deg_hist(const int* __restrict__ dst, const float* __restrict__ ew,
                           float* __restrict__ deg, int* __restrict__ hist) {
  int e = blockIdx.x * blockDim.x + threadIdx.x;
  if (e < NE) {
    int d = dst[e];
    atomicAdd(&deg[d], ew[e]);
    atomicAdd(&hist[d], 1);
  }
}

__global__ void k_dinv(float* deg) {
  int i = blockIdx.x * blockDim.x + threadIdx.x;
  if (i < NN) deg[i] = rsqrtf(deg[i]);  // deg >= 1 always
}

__global__ void k_norm(const int* __restrict__ src, const int* __restrict__ dst,
                       const float* __restrict__ ew, const float* __restrict__ dinv,
                       float* __restrict__ norm) {
  int e = blockIdx.x * blockDim.x + threadIdx.x;
  if (e < NE) norm[e] = dinv[src[e]] * ew[e] * dinv[dst[e]];
}

// ---------------- exclusive scan (3-phase) ----------------
__global__ __launch_bounds__(512) void k_scan_a(const int* __restrict__ hist,
                                                int* __restrict__ part,
                                                int* __restrict__ bsum) {
  __shared__ int sh[512];
  int t = threadIdx.x;
  int gid = blockIdx.x * 512 + t;
  int v = (gid < NN) ? hist[gid] : 0;
  sh[t] = v;
  __syncthreads();
  #pragma unroll
  for (int off = 1; off < 512; off <<= 1) {
    int u = (t >= off) ? sh[t - off] : 0;
    __syncthreads();
    sh[t] += u;
    __syncthreads();
  }
  if (gid < NN) part[gid] = sh[t] - v;           // exclusive
  if (t == 511) bsum[blockIdx.x] = sh[511];      // block total
}

__global__ __launch_bounds__(256) void k_scan_b(int* __restrict__ bsum) {
  __shared__ int sh[256];
  int t = threadIdx.x;
  int v = (t < NBLK) ? bsum[t] : 0;
  sh[t] = v;
  __syncthreads();
  #pragma unroll
  for (int off = 1; off < 256; off <<= 1) {
    int u = (t >= off) ? sh[t - off] : 0;
    __syncthreads();
    sh[t] += u;
    __syncthreads();
  }
  if (t < NBLK) bsum[t] = sh[t] - v;             // exclusive block offsets
}

__global__ void k_scan_c(const int* __restrict__ part, const int* __restrict__ bsum,
                         int* __restrict__ rowptr, int* __restrict__ cursor) {
  int i = blockIdx.x * blockDim.x + threadIdx.x;
  if (i < NN) {
    int v = part[i] + bsum[i >> 9];
    rowptr[i] = v;
    cursor[i] = v;
  }
  if (i == 0) rowptr[NN] = NE;
}

// ---------------- CSR fill ----------------
__global__ void k_fill(const int* __restrict__ src, const int* __restrict__ dst,
                       const float* __restrict__ norm, int* __restrict__ cursor,
                       int* __restrict__ csr_src, float* __restrict__ csr_norm) {
  int e = blockIdx.x * blockDim.x + threadIdx.x;
  if (e < NE) {
    int d = dst[e];
    int pos = atomicAdd(&cursor[d], 1);
    csr_src[pos] = src[e];
    csr_norm[pos] = norm[e];
  }
}

// ---------------- GEMM: C[M,128] = A[M,128] @ W[128,128] ----------------
__global__ __launch_bounds__(256) void k_gemm128(const float* __restrict__ A,
                                                 const float* __restrict__ W,
                                                 float* __restrict__ C, int M) {
  __shared__ float As[128][132];
  __shared__ float Ws[128][128];
  const int t = threadIdx.x;
  const int row0 = blockIdx.x * 128;

  const float4* W4 = reinterpret_cast<const float4*>(W);
  for (int i = t; i < 4096; i += 256) {
    float4 v = W4[i];
    int fi = i * 4; int r = fi >> 7; int c = fi & 127;
    *reinterpret_cast<float4*>(&Ws[r][c]) = v;
  }
  const float4* A4 = reinterpret_cast<const float4*>(A);
  for (int i = t; i < 4096; i += 256) {
    int fi = i * 4; int r = fi >> 7; int c = fi & 127;
    float4 v = make_float4(0.f, 0.f, 0.f, 0.f);
    if (row0 + r < M) v = A4[((size_t)(row0 + r) * HD + c) >> 2];
    *reinterpret_cast<float4*>(&As[r][c]) = v;
  }
  __syncthreads();

  const int rg = t >> 3;   // 0..31
  const int cg = t & 7;    // 0..7
  float acc[4][16];
  #pragma unroll
  for (int i = 0; i < 4; ++i)
    #pragma unroll
    for (int j = 0; j < 16; ++j) acc[i][j] = 0.f;

  for (int k = 0; k < 128; ++k) {
    float a[4];
    #pragma unroll
    for (int i = 0; i < 4; ++i) a[i] = As[32 * i + rg][k];
    #pragma unroll
    for (int q = 0; q < 4; ++q) {
      float4 w = *reinterpret_cast<const float4*>(&Ws[k][cg * 4 + 32 * q]);
      #pragma unroll
      for (int i = 0; i < 4; ++i) {
        acc[i][q * 4 + 0] += a[i] * w.x;
        acc[i][q * 4 + 1] += a[i] * w.y;
        acc[i][q * 4 + 2] += a[i] * w.z;
        acc[i][q * 4 + 3] += a[i] * w.w;
      }
    }
  }

  #pragma unroll
  for (int i = 0; i < 4; ++i) {
    int row = row0 + 32 * i + rg;
    if (row < M) {
      #pragma unroll
      for (int q = 0; q < 4; ++q) {
        float4 v = make_float4(acc[i][q * 4 + 0], acc[i][q * 4 + 1],
                               acc[i][q * 4 + 2], acc[i][q * 4 + 3]);
        *reinterpret_cast<float4*>(&C[(size_t)row * HD + cg * 4 + 32 * q]) = v;
      }
    }
  }
}

// ---------------- pull aggregation, fused self-loop + bias + relu ----------------
// 32 lanes per node, one float4 column-slice per lane.
// out[n] = relu( bias + dinv[n]^2 * x[self] + sum_e norm[e] * x[src[e]] )
template <bool IND>
__global__ __launch_bounds__(256) void k_agg(const float* __restrict__ xw,
                                             const int* __restrict__ xidx,
                                             const int* __restrict__ rowptr,
                                             const int* __restrict__ csr_src,
                                             const float* __restrict__ csr_norm,
                                             const float* __restrict__ dinv,
                                             const float* __restrict__ bias,
                                             float* __restrict__ outp) {
  int tid = blockIdx.x * blockDim.x + threadIdx.x;
  int n = tid >> 5, lane = tid & 31;
  if (n >= NN) return;
  int beg = rowptr[n], end = rowptr[n + 1];
  float4 acc = make_float4(0.f, 0.f, 0.f, 0.f);
  int e = beg;
  for (; e + 1 < end; e += 2) {        // unroll-2: two row loads in flight
    int s0 = csr_src[e], s1 = csr_src[e + 1];
    if (IND) { s0 = xidx[s0]; s1 = xidx[s1]; }
    float c0 = csr_norm[e], c1 = csr_norm[e + 1];
    float4 v0 = reinterpret_cast<const float4*>(xw + (size_t)s0 * HD)[lane];
    float4 v1 = reinterpret_cast<const float4*>(xw + (size_t)s1 * HD)[lane];
    acc.x += c0 * v0.x + c1 * v1.x;
    acc.y += c0 * v0.y + c1 * v1.y;
    acc.z += c0 * v0.z + c1 * v1.z;
    acc.w += c0 * v0.w + c1 * v1.w;
  }
  if (e < end) {
    int s0 = csr_src[e];
    if (IND) s0 = xidx[s0];
    float c0 = csr_norm[e];
    float4 v0 = reinterpret_cast<const float4*>(xw + (size_t)s0 * HD)[lane];
    acc.x += c0 * v0.x; acc.y += c0 * v0.y;
    acc.z += c0 * v0.z; acc.w += c0 * v0.w;
  }
  int sn = IND ? xidx[n] : n;
  float d = dinv[n];
  float cs = d * d;
  float4 v = reinterpret_cast<const float4*>(xw + (size_t)sn * HD)[lane];
  float4 bb = reinterpret_cast<const float4*>(bias)[lane];
  acc.x = fmaxf(acc.x + cs * v.x + bb.x, 0.f);
  acc.y = fmaxf(acc.y + cs * v.y + bb.y, 0.f);
  acc.z = fmaxf(acc.z + cs * v.z + bb.z, 0.f);
  acc.w = fmaxf(acc.w + cs * v.w + bb.w, 0.f);
  reinterpret_cast<float4*>(outp + (size_t)n * HD)[lane] = acc;
}

// ---------------- pooling ----------------
__global__ void k_zero(float* p, int n) {
  int i = blockIdx.x * blockDim.x + threadIdx.x;
  if (i < n) p[i] = 0.f;
}

__global__ void k_pool(const float* __restrict__ x, const int* __restrict__ batch,
                       float* __restrict__ sums) {
  int tid = blockIdx.x * blockDim.x + threadIdx.x;
  int g = tid >> 5, lane = tid & 31;
  int n0 = g * 8;
  if (n0 >= NN) return;
  int nend = min(n0 + 8, NN);
  float4 acc = make_float4(0.f, 0.f, 0.f, 0.f);
  int curb = batch[n0];
  for (int n = n0; n < nend; ++n) {
    int b = batch[n];
    if (b != curb) {
      float* o = sums + (size_t)curb * HD + lane * 4;
      atomicAdd(o + 0, acc.x); atomicAdd(o + 1, acc.y);
      atomicAdd(o + 2, acc.z); atomicAdd(o + 3, acc.w);
      acc = make_float4(0.f, 0.f, 0.f, 0.f);
      curb = b;
    }
    float4 v = reinterpret_cast<const float4*>(x + (size_t)n * HD)[lane];
    acc.x += v.x; acc.y += v.y; acc.z += v.z; acc.w += v.w;
  }
  float* o = sums + (size_t)curb * HD + lane * 4;
  atomicAdd(o + 0, acc.x); atomicAdd(o + 1, acc.y);
  atomicAdd(o + 2, acc.z); atomicAdd(o + 3, acc.w);
}

__global__ void k_counts(const int* __restrict__ batch, float* __restrict__ cnt) {
  int b = threadIdx.x;
  if (b >= NB) return;
  auto lb = [&](int v) {
    int lo = 0, hi = NN;
    while (lo < hi) { int m = (lo + hi) >> 1; if (batch[m] < v) lo = m + 1; else hi = m; }
    return lo;
  };
  cnt[b] = (float)(lb(b + 1) - lb(b));
}

// ---------------- MLP head + softmax ----------------
__global__ __launch_bounds__(64) void k_head(const float* __restrict__ sums,
                                             const float* __restrict__ cnt,
                                             const float* __restrict__ W1,
                                             const float* __restrict__ b1,
                                             const float* __restrict__ W2,
                                             const float* __restrict__ b2,
                                             float* __restrict__ out) {
  int g = blockIdx.x, t = threadIdx.x;  // 64 threads
  __shared__ float gv[128];
  __shared__ float h[64];
  __shared__ float logits[2];
  float c = fmaxf(cnt[g], 1.0f);
  gv[t] = sums[g * HD + t] / c;
  gv[t + 64] = sums[g * HD + 64 + t] / c;
  __syncthreads();
  float acc = b1[t];
  for (int k = 0; k < 128; ++k) acc += gv[k] * W1[k * 64 + t];
  h[t] = fmaxf(acc, 0.f);
  __syncthreads();
  if (t < 2) {
    float a = b2[t];
    for (int j = 0; j < 64; ++j) a += h[j] * W2[j * 2 + t];
    logits[t] = a;
  }
  __syncthreads();
  if (t < 2) {
    float m = fmaxf(logits[0], logits[1]);
    float e0 = __expf(logits[0] - m), e1 = __expf(logits[1] - m);
    out[g * 2 + t] = (t == 0 ? e0 : e1) / (e0 + e1);
  }
}

// ---------------- launch ----------------
extern "C" void kernel_launch(void* const* d_in, const int* in_sizes, int n_in,
                              void* d_out, int out_size, void* d_ws, size_t ws_size,
                              hipStream_t stream) {
  const int*   x_idx = (const int*)d_in[0];
  const int*   eidx  = (const int*)d_in[1];
  const float* ew    = (const float*)d_in[2];
  const int*   batch = (const int*)d_in[3];
  const float* emb   = (const float*)d_in[4];
  const float* W1    = (const float*)d_in[5];
  const float* b1    = (const float*)d_in[6];
  const float* W2    = (const float*)d_in[7];
  const float* b2    = (const float*)d_in[8];
  const float* mW1   = (const float*)d_in[9];
  const float* mb1   = (const float*)d_in[10];
  const float* mW2   = (const float*)d_in[11];
  const float* mb2   = (const float*)d_in[12];
  const int* src = eidx;
  const int* dst = eidx + NE;
  float* out = (float*)d_out;

  char* ws = (char*)d_ws;
  size_t off = 0;
  auto alloc = [&](size_t bytes) {
    void* p = ws + off;
    off += (bytes + 255) & ~(size_t)255;
    return p;
  };
  float* dinv    = (float*)alloc((size_t)NN * 4);
  float* norm    = (float*)alloc((size_t)NE * 4);
  int*   hist    = (int*)alloc((size_t)NN * 4);
  int*   part    = (int*)alloc((size_t)NN * 4);
  int*   bsum    = (int*)alloc((size_t)256 * 4);
  int*   rowptr  = (int*)alloc((size_t)(NN + 1) * 4);
  int*   cursor  = (int*)alloc((size_t)NN * 4);
  int*   csr_src = (int*)alloc((size_t)NE * 4);
  float* csr_nrm = (float*)alloc((size_t)NE * 4);
  float* embW    = (float*)alloc((size_t)NV * HD * 4);
  float* bufA    = (float*)alloc((size_t)NN * HD * 4);
  float* bufB    = (float*)alloc((size_t)NN * HD * 4);
  float* sums    = (float*)alloc((size_t)NB * HD * 4);
  float* cnt     = (float*)alloc((size_t)NB * 4);

  // degree + in-degree histogram
  k_init<<<(NN + 255) / 256, 256, 0, stream>>>(dinv, hist);
  k_deg_hist<<<(NE + 255) / 256, 256, 0, stream>>>(dst, ew, dinv, hist);
  k_dinv<<<(NN + 255) / 256, 256, 0, stream>>>(dinv);
  k_norm<<<(NE + 255) / 256, 256, 0, stream>>>(src, dst, ew, dinv, norm);

  // CSR build: scan + fill
  k_scan_a<<<NBLK, 512, 0, stream>>>(hist, part, bsum);
  k_scan_b<<<1, 256, 0, stream>>>(bsum);
  k_scan_c<<<(NN + 255) / 256, 256, 0, stream>>>(part, bsum, rowptr, cursor);
  k_fill<<<(NE + 255) / 256, 256, 0, stream>>>(src, dst, norm, cursor, csr_src, csr_nrm);

  // embW = emb_table @ W1  (conv1's xW is a gather of embW)
  k_gemm128<<<(NV + 127) / 128, 256, 0, stream>>>(emb, W1, embW, NV);

  // conv1: bufB = relu(agg(embW[xidx]) + b1)
  k_agg<true><<<(int)(((size_t)NN * 32 + 255) / 256), 256, 0, stream>>>(
      embW, x_idx, rowptr, csr_src, csr_nrm, dinv, b1, bufB);

  // conv2: bufA = h1 @ W2 ; bufB = relu(agg(bufA) + b2)
  k_gemm128<<<(NN + 127) / 128, 256, 0, stream>>>(bufB, W2, bufA, NN);
  k_agg<false><<<(int)(((size_t)NN * 32 + 255) / 256), 256, 0, stream>>>(
      bufA, nullptr, rowptr, csr_src, csr_nrm, dinv, b2, bufB);

  // pool + head
  k_zero<<<(NB * HD + 255) / 256, 256, 0, stream>>>(sums, NB * HD);
  k_pool<<<((NN + 7) / 8 * 32 + 255) / 256, 256, 0, stream>>>(bufB, batch, sums);
  k_counts<<<1, 128, 0, stream>>>(batch, cnt);
  k_head<<<NB, 64, 0, stream>>>(sums, cnt, mW1, mb1, mW2, mb2, out);
}

// Round 3
// 555.100 us; speedup vs baseline: 10.2923x; 1.2289x over previous
//
#include <hip/hip_runtime.h>
#include <hip/hip_bf16.h>

#define NN 100000      // nodes
#define NE 1600000     // edges
#define NB 128         // graphs
#define NV 10000       // vocab
#define HD 128         // emb = hid = 128
#define NBLK 196       // ceil(NN/512) for scan

#define FIX_SCALE 16777216.0f          // 2^24 fixed-point scale for edge weights
#define SUM_MASK  0xFFFFFFFFFFULL      // low 40 bits hold the weighted-degree sum

// ---------------- init packed deg/hist accumulator ----------------
__global__ void k_init(unsigned long long* packed) {
  int i = blockIdx.x * blockDim.x + threadIdx.x;
  if (i < NN) packed[i] = 0ULL;
}

// one 64-bit atomic per edge: count in bits [40,64), fixed-point ew sum in [0,40)
__global__ void k_deg_hist(const int* __restrict__ dst, const float* __restrict__ ew,
                           unsigned long long* __restrict__ packed) {
  int e = blockIdx.x * blockDim.x + threadIdx.x;
  if (e < NE) {
    unsigned long long fx = (unsigned long long)__float2uint_rn(ew[e] * FIX_SCALE);
    atomicAdd(&packed[dst[e]], (1ULL << 40) | fx);
  }
}

// ---------------- exclusive scan (3-phase) + dinv unpack ----------------
__global__ __launch_bounds__(512) void k_scan_a(const unsigned long long* __restrict__ packed,
                                                int* __restrict__ part,
                                                int* __restrict__ bsum,
                                                float* __restrict__ dinv) {
  __shared__ int sh[512];
  int t = threadIdx.x;
  int gid = blockIdx.x * 512 + t;
  unsigned long long p = (gid < NN) ? packed[gid] : 0ULL;
  int v = (int)(p >> 40);
  if (gid < NN)
    dinv[gid] = rsqrtf(1.0f + (float)(p & SUM_MASK) * (1.0f / FIX_SCALE));
  sh[t] = v;
  __syncthreads();
  #pragma unroll
  for (int off = 1; off < 512; off <<= 1) {
    int u = (t >= off) ? sh[t - off] : 0;
    __syncthreads();
    sh[t] += u;
    __syncthreads();
  }
  if (gid < NN) part[gid] = sh[t] - v;           // exclusive
  if (t == 511) bsum[blockIdx.x] = sh[511];      // block total
}

__global__ __launch_bounds__(256) void k_scan_b(int* __restrict__ bsum) {
  __shared__ int sh[256];
  int t = threadIdx.x;
  int v = (t < NBLK) ? bsum[t] : 0;
  sh[t] = v;
  __syncthreads();
  #pragma unroll
  for (int off = 1; off < 256; off <<= 1) {
    int u = (t >= off) ? sh[t - off] : 0;
    __syncthreads();
    sh[t] += u;
    __syncthreads();
  }
  if (t < NBLK) bsum[t] = sh[t] - v;             // exclusive block offsets
}

__global__ void k_scan_c(const int* __restrict__ part, const int* __restrict__ bsum,
                         int* __restrict__ rowptr, int* __restrict__ cursor) {
  int i = blockIdx.x * blockDim.x + threadIdx.x;
  if (i < NN) {
    int v = part[i] + bsum[i >> 9];
    rowptr[i] = v;
    cursor[i] = v;
  }
  if (i == 0) rowptr[NN] = NE;
}

// ---------------- CSR fill: packed (src, norm) in one 8B store ----------------
__global__ void k_fill(const int* __restrict__ src, const int* __restrict__ dst,
                       const float* __restrict__ ew, const float* __restrict__ dinv,
                       int* __restrict__ cursor, uint2* __restrict__ csr) {
  int e = blockIdx.x * blockDim.x + threadIdx.x;
  if (e < NE) {
    int s = src[e], d = dst[e];
    float nrm = dinv[s] * ew[e] * dinv[d];
    int pos = atomicAdd(&cursor[d], 1);
    csr[pos] = make_uint2((unsigned)s, __float_as_uint(nrm));
  }
}

// ---------------- GEMM: C[M,128] = A[M,128] @ W[128,128] ----------------
__global__ __launch_bounds__(256) void k_gemm128(const float* __restrict__ A,
                                                 const float* __restrict__ W,
                                                 float* __restrict__ C, int M) {
  __shared__ float As[128][132];
  __shared__ float Ws[128][128];
  const int t = threadIdx.x;
  const int row0 = blockIdx.x * 128;

  const float4* W4 = reinterpret_cast<const float4*>(W);
  for (int i = t; i < 4096; i += 256) {
    float4 v = W4[i];
    int fi = i * 4; int r = fi >> 7; int c = fi & 127;
    *reinterpret_cast<float4*>(&Ws[r][c]) = v;
  }
  const float4* A4 = reinterpret_cast<const float4*>(A);
  for (int i = t; i < 4096; i += 256) {
    int fi = i * 4; int r = fi >> 7; int c = fi & 127;
    float4 v = make_float4(0.f, 0.f, 0.f, 0.f);
    if (row0 + r < M) v = A4[((size_t)(row0 + r) * HD + c) >> 2];
    *reinterpret_cast<float4*>(&As[r][c]) = v;
  }
  __syncthreads();

  const int rg = t >> 3;   // 0..31
  const int cg = t & 7;    // 0..7
  float acc[4][16];
  #pragma unroll
  for (int i = 0; i < 4; ++i)
    #pragma unroll
    for (int j = 0; j < 16; ++j) acc[i][j] = 0.f;

  for (int k = 0; k < 128; ++k) {
    float a[4];
    #pragma unroll
    for (int i = 0; i < 4; ++i) a[i] = As[32 * i + rg][k];
    #pragma unroll
    for (int q = 0; q < 4; ++q) {
      float4 w = *reinterpret_cast<const float4*>(&Ws[k][cg * 4 + 32 * q]);
      #pragma unroll
      for (int i = 0; i < 4; ++i) {
        acc[i][q * 4 + 0] += a[i] * w.x;
        acc[i][q * 4 + 1] += a[i] * w.y;
        acc[i][q * 4 + 2] += a[i] * w.z;
        acc[i][q * 4 + 3] += a[i] * w.w;
      }
    }
  }

  #pragma unroll
  for (int i = 0; i < 4; ++i) {
    int row = row0 + 32 * i + rg;
    if (row < M) {
      #pragma unroll
      for (int q = 0; q < 4; ++q) {
        float4 v = make_float4(acc[i][q * 4 + 0], acc[i][q * 4 + 1],
                               acc[i][q * 4 + 2], acc[i][q * 4 + 3]);
        *reinterpret_cast<float4*>(&C[(size_t)row * HD + cg * 4 + 32 * q]) = v;
      }
    }
  }
}

// ---------------- pull aggregation, fused self-loop + bias + relu ----------------
// 32 lanes per node, one float4 column-slice per lane.
template <bool IND>
__global__ __launch_bounds__(256) void k_agg(const float* __restrict__ xw,
                                             const int* __restrict__ xidx,
                                             const int* __restrict__ rowptr,
                                             const uint2* __restrict__ csr,
                                             const float* __restrict__ dinv,
                                             const float* __restrict__ bias,
                                             float* __restrict__ outp) {
  int tid = blockIdx.x * blockDim.x + threadIdx.x;
  int n = tid >> 5, lane = tid & 31;
  if (n >= NN) return;
  int beg = rowptr[n], end = rowptr[n + 1];
  float4 acc = make_float4(0.f, 0.f, 0.f, 0.f);
  int e = beg;
  for (; e + 1 < end; e += 2) {        // unroll-2: two row loads in flight
    uint2 p0 = csr[e], p1 = csr[e + 1];
    int s0 = (int)p0.x, s1 = (int)p1.x;
    float c0 = __uint_as_float(p0.y), c1 = __uint_as_float(p1.y);
    if (IND) { s0 = xidx[s0]; s1 = xidx[s1]; }
    float4 v0 = reinterpret_cast<const float4*>(xw + (size_t)s0 * HD)[lane];
    float4 v1 = reinterpret_cast<const float4*>(xw + (size_t)s1 * HD)[lane];
    acc.x += c0 * v0.x + c1 * v1.x;
    acc.y += c0 * v0.y + c1 * v1.y;
    acc.z += c0 * v0.z + c1 * v1.z;
    acc.w += c0 * v0.w + c1 * v1.w;
  }
  if (e < end) {
    uint2 p0 = csr[e];
    int s0 = (int)p0.x;
    float c0 = __uint_as_float(p0.y);
    if (IND) s0 = xidx[s0];
    float4 v0 = reinterpret_cast<const float4*>(xw + (size_t)s0 * HD)[lane];
    acc.x += c0 * v0.x; acc.y += c0 * v0.y;
    acc.z += c0 * v0.z; acc.w += c0 * v0.w;
  }
  int sn = IND ? xidx[n] : n;
  float d = dinv[n];
  float cs = d * d;
  float4 v = reinterpret_cast<const float4*>(xw + (size_t)sn * HD)[lane];
  float4 bb = reinterpret_cast<const float4*>(bias)[lane];
  acc.x = fmaxf(acc.x + cs * v.x + bb.x, 0.f);
  acc.y = fmaxf(acc.y + cs * v.y + bb.y, 0.f);
  acc.z = fmaxf(acc.z + cs * v.z + bb.z, 0.f);
  acc.w = fmaxf(acc.w + cs * v.w + bb.w, 0.f);
  reinterpret_cast<float4*>(outp + (size_t)n * HD)[lane] = acc;
}

// ---------------- pooling ----------------
__global__ void k_zero(float* p, int n) {
  int i = blockIdx.x * blockDim.x + threadIdx.x;
  if (i < n) p[i] = 0.f;
}

__global__ void k_pool(const float* __restrict__ x, const int* __restrict__ batch,
                       float* __restrict__ sums) {
  int tid = blockIdx.x * blockDim.x + threadIdx.x;
  int g = tid >> 5, lane = tid & 31;
  int n0 = g * 8;
  if (n0 >= NN) return;
  int nend = min(n0 + 8, NN);
  float4 acc = make_float4(0.f, 0.f, 0.f, 0.f);
  int curb = batch[n0];
  for (int n = n0; n < nend; ++n) {
    int b = batch[n];
    if (b != curb) {
      float* o = sums + (size_t)curb * HD + lane * 4;
      atomicAdd(o + 0, acc.x); atomicAdd(o + 1, acc.y);
      atomicAdd(o + 2, acc.z); atomicAdd(o + 3, acc.w);
      acc = make_float4(0.f, 0.f, 0.f, 0.f);
      curb = b;
    }
    float4 v = reinterpret_cast<const float4*>(x + (size_t)n * HD)[lane];
    acc.x += v.x; acc.y += v.y; acc.z += v.z; acc.w += v.w;
  }
  float* o = sums + (size_t)curb * HD + lane * 4;
  atomicAdd(o + 0, acc.x); atomicAdd(o + 1, acc.y);
  atomicAdd(o + 2, acc.z); atomicAdd(o + 3, acc.w);
}

__global__ void k_counts(const int* __restrict__ batch, float* __restrict__ cnt) {
  int b = threadIdx.x;
  if (b >= NB) return;
  auto lb = [&](int v) {
    int lo = 0, hi = NN;
    while (lo < hi) { int m = (lo + hi) >> 1; if (batch[m] < v) lo = m + 1; else hi = m; }
    return lo;
  };
  cnt[b] = (float)(lb(b + 1) - lb(b));
}

// ---------------- MLP head + softmax ----------------
__global__ __launch_bounds__(64) void k_head(const float* __restrict__ sums,
                                             const float* __restrict__ cnt,
                                             const float* __restrict__ W1,
                                             const float* __restrict__ b1,
                                             const float* __restrict__ W2,
                                             const float* __restrict__ b2,
                                             float* __restrict__ out) {
  int g = blockIdx.x, t = threadIdx.x;  // 64 threads
  __shared__ float gv[128];
  __shared__ float h[64];
  __shared__ float logits[2];
  float c = fmaxf(cnt[g], 1.0f);
  gv[t] = sums[g * HD + t] / c;
  gv[t + 64] = sums[g * HD + 64 + t] / c;
  __syncthreads();
  float acc = b1[t];
  for (int k = 0; k < 128; ++k) acc += gv[k] * W1[k * 64 + t];
  h[t] = fmaxf(acc, 0.f);
  __syncthreads();
  if (t < 2) {
    float a = b2[t];
    for (int j = 0; j < 64; ++j) a += h[j] * W2[j * 2 + t];
    logits[t] = a;
  }
  __syncthreads();
  if (t < 2) {
    float m = fmaxf(logits[0], logits[1]);
    float e0 = __expf(logits[0] - m), e1 = __expf(logits[1] - m);
    out[g * 2 + t] = (t == 0 ? e0 : e1) / (e0 + e1);
  }
}

// ---------------- launch ----------------
extern "C" void kernel_launch(void* const* d_in, const int* in_sizes, int n_in,
                              void* d_out, int out_size, void* d_ws, size_t ws_size,
                              hipStream_t stream) {
  const int*   x_idx = (const int*)d_in[0];
  const int*   eidx  = (const int*)d_in[1];
  const float* ew    = (const float*)d_in[2];
  const int*   batch = (const int*)d_in[3];
  const float* emb   = (const float*)d_in[4];
  const float* W1    = (const float*)d_in[5];
  const float* b1    = (const float*)d_in[6];
  const float* W2    = (const float*)d_in[7];
  const float* b2    = (const float*)d_in[8];
  const float* mW1   = (const float*)d_in[9];
  const float* mb1   = (const float*)d_in[10];
  const float* mW2   = (const float*)d_in[11];
  const float* mb2   = (const float*)d_in[12];
  const int* src = eidx;
  const int* dst = eidx + NE;
  float* out = (float*)d_out;

  char* ws = (char*)d_ws;
  size_t off = 0;
  auto alloc = [&](size_t bytes) {
    void* p = ws + off;
    off += (bytes + 255) & ~(size_t)255;
    return p;
  };
  unsigned long long* packed = (unsigned long long*)alloc((size_t)NN * 8);
  float* dinv    = (float*)alloc((size_t)NN * 4);
  int*   part    = (int*)alloc((size_t)NN * 4);
  int*   bsum    = (int*)alloc((size_t)256 * 4);
  int*   rowptr  = (int*)alloc((size_t)(NN + 1) * 4);
  int*   cursor  = (int*)alloc((size_t)NN * 4);
  uint2* csr     = (uint2*)alloc((size_t)NE * 8);
  float* embW    = (float*)alloc((size_t)NV * HD * 4);
  float* bufA    = (float*)alloc((size_t)NN * HD * 4);
  float* bufB    = (float*)alloc((size_t)NN * HD * 4);
  float* sums    = (float*)alloc((size_t)NB * HD * 4);
  float* cnt     = (float*)alloc((size_t)NB * 4);

  // degree + in-degree histogram (single packed 64-bit atomic per edge)
  k_init<<<(NN + 255) / 256, 256, 0, stream>>>(packed);
  k_deg_hist<<<(NE + 255) / 256, 256, 0, stream>>>(dst, ew, packed);

  // CSR build: scan (computes dinv too) + fill (computes norm inline)
  k_scan_a<<<NBLK, 512, 0, stream>>>(packed, part, bsum, dinv);
  k_scan_b<<<1, 256, 0, stream>>>(bsum);
  k_scan_c<<<(NN + 255) / 256, 256, 0, stream>>>(part, bsum, rowptr, cursor);
  k_fill<<<(NE + 255) / 256, 256, 0, stream>>>(src, dst, ew, dinv, cursor, csr);

  // embW = emb_table @ W1  (conv1's xW is a gather of embW)
  k_gemm128<<<(NV + 127) / 128, 256, 0, stream>>>(emb, W1, embW, NV);

  // conv1: bufB = relu(agg(embW[xidx]) + b1)
  k_agg<true><<<(int)(((size_t)NN * 32 + 255) / 256), 256, 0, stream>>>(
      embW, x_idx, rowptr, csr, dinv, b1, bufB);

  // conv2: bufA = h1 @ W2 ; bufB = relu(agg(bufA) + b2)
  k_gemm128<<<(NN + 127) / 128, 256, 0, stream>>>(bufB, W2, bufA, NN);
  k_agg<false><<<(int)(((size_t)NN * 32 + 255) / 256), 256, 0, stream>>>(
      bufA, nullptr, rowptr, csr, dinv, b2, bufB);

  // pool + head
  k_zero<<<(NB * HD + 255) / 256, 256, 0, stream>>>(sums, NB * HD);
  k_pool<<<((NN + 7) / 8 * 32 + 255) / 256, 256, 0, stream>>>(bufB, batch, sums);
  k_counts<<<1, 128, 0, stream>>>(batch, cnt);
  k_head<<<NB, 64, 0, stream>>>(sums, cnt, mW1, mb1, mW2, mb2, out);
}

// Round 4
// 484.441 us; speedup vs baseline: 11.7935x; 1.1459x over previous
//
#include <hip/hip_runtime.h>
#include <hip/hip_bf16.h>

#define NN 100000      // nodes
#define NE 1600000     // edges
#define NB 128         // graphs
#define NV 10000       // vocab
#define HD 128         // emb = hid = 128
#define NBLK 196       // ceil(NN/512) for scan

#define FIX_SCALE 16777216.0f          // 2^24 fixed-point scale for edge weights
#define SUM_MASK  0xFFFFFFFFFFULL      // low 40 bits hold the weighted-degree sum

__device__ __forceinline__ float bf2f(unsigned short b) {
  return __uint_as_float((unsigned)b << 16);
}
__device__ __forceinline__ unsigned short f2bf(float f) {
  __hip_bfloat16 h = __float2bfloat16(f);   // RNE
  return *reinterpret_cast<unsigned short*>(&h);
}

// ---------------- init packed deg/hist accumulator ----------------
__global__ void k_init(unsigned long long* packed) {
  int i = blockIdx.x * blockDim.x + threadIdx.x;
  if (i < NN) packed[i] = 0ULL;
}

// one 64-bit atomic per edge: count in bits [40,64), fixed-point ew sum in [0,40)
__global__ void k_deg_hist(const int* __restrict__ dst, const float* __restrict__ ew,
                           unsigned long long* __restrict__ packed) {
  int e = blockIdx.x * blockDim.x + threadIdx.x;
  if (e < NE) {
    unsigned long long fx = (unsigned long long)__float2uint_rn(ew[e] * FIX_SCALE);
    atomicAdd(&packed[dst[e]], (1ULL << 40) | fx);
  }
}

// ---------------- exclusive scan (3-phase) + dinv unpack ----------------
__global__ __launch_bounds__(512) void k_scan_a(const unsigned long long* __restrict__ packed,
                                                int* __restrict__ part,
                                                int* __restrict__ bsum,
                                                float* __restrict__ dinv) {
  __shared__ int sh[512];
  int t = threadIdx.x;
  int gid = blockIdx.x * 512 + t;
  unsigned long long p = (gid < NN) ? packed[gid] : 0ULL;
  int v = (int)(p >> 40);
  if (gid < NN)
    dinv[gid] = rsqrtf(1.0f + (float)(p & SUM_MASK) * (1.0f / FIX_SCALE));
  sh[t] = v;
  __syncthreads();
  #pragma unroll
  for (int off = 1; off < 512; off <<= 1) {
    int u = (t >= off) ? sh[t - off] : 0;
    __syncthreads();
    sh[t] += u;
    __syncthreads();
  }
  if (gid < NN) part[gid] = sh[t] - v;           // exclusive
  if (t == 511) bsum[blockIdx.x] = sh[511];      // block total
}

__global__ __launch_bounds__(256) void k_scan_b(int* __restrict__ bsum) {
  __shared__ int sh[256];
  int t = threadIdx.x;
  int v = (t < NBLK) ? bsum[t] : 0;
  sh[t] = v;
  __syncthreads();
  #pragma unroll
  for (int off = 1; off < 256; off <<= 1) {
    int u = (t >= off) ? sh[t - off] : 0;
    __syncthreads();
    sh[t] += u;
    __syncthreads();
  }
  if (t < NBLK) bsum[t] = sh[t] - v;             // exclusive block offsets
}

__global__ void k_scan_c(const int* __restrict__ part, const int* __restrict__ bsum,
                         int* __restrict__ rowptr, int* __restrict__ cursor) {
  int i = blockIdx.x * blockDim.x + threadIdx.x;
  if (i < NN) {
    int v = part[i] + bsum[i >> 9];
    rowptr[i] = v;
    cursor[i] = v;
  }
  if (i == 0) rowptr[NN] = NE;
}

// ---------------- CSR fill: packed (src, norm) in one 8B store ----------------
__global__ void k_fill(const int* __restrict__ src, const int* __restrict__ dst,
                       const float* __restrict__ ew, const float* __restrict__ dinv,
                       int* __restrict__ cursor, uint2* __restrict__ csr) {
  int e = blockIdx.x * blockDim.x + threadIdx.x;
  if (e < NE) {
    int s = src[e], d = dst[e];
    float nrm = dinv[s] * ew[e] * dinv[d];
    int pos = atomicAdd(&cursor[d], 1);
    csr[pos] = make_uint2((unsigned)s, __float_as_uint(nrm));
  }
}

// ---------------- GEMM: C[M,128] = A[M,128] @ W[128,128], C stored bf16 ----------------
__global__ __launch_bounds__(256) void k_gemm128(const float* __restrict__ A,
                                                 const float* __restrict__ W,
                                                 unsigned short* __restrict__ C, int M) {
  __shared__ float As[128][132];
  __shared__ float Ws[128][128];
  const int t = threadIdx.x;
  const int row0 = blockIdx.x * 128;

  const float4* W4 = reinterpret_cast<const float4*>(W);
  for (int i = t; i < 4096; i += 256) {
    float4 v = W4[i];
    int fi = i * 4; int r = fi >> 7; int c = fi & 127;
    *reinterpret_cast<float4*>(&Ws[r][c]) = v;
  }
  const float4* A4 = reinterpret_cast<const float4*>(A);
  for (int i = t; i < 4096; i += 256) {
    int fi = i * 4; int r = fi >> 7; int c = fi & 127;
    float4 v = make_float4(0.f, 0.f, 0.f, 0.f);
    if (row0 + r < M) v = A4[((size_t)(row0 + r) * HD + c) >> 2];
    *reinterpret_cast<float4*>(&As[r][c]) = v;
  }
  __syncthreads();

  const int rg = t >> 3;   // 0..31
  const int cg = t & 7;    // 0..7
  float acc[4][16];
  #pragma unroll
  for (int i = 0; i < 4; ++i)
    #pragma unroll
    for (int j = 0; j < 16; ++j) acc[i][j] = 0.f;

  for (int k = 0; k < 128; ++k) {
    float a[4];
    #pragma unroll
    for (int i = 0; i < 4; ++i) a[i] = As[32 * i + rg][k];
    #pragma unroll
    for (int q = 0; q < 4; ++q) {
      float4 w = *reinterpret_cast<const float4*>(&Ws[k][cg * 4 + 32 * q]);
      #pragma unroll
      for (int i = 0; i < 4; ++i) {
        acc[i][q * 4 + 0] += a[i] * w.x;
        acc[i][q * 4 + 1] += a[i] * w.y;
        acc[i][q * 4 + 2] += a[i] * w.z;
        acc[i][q * 4 + 3] += a[i] * w.w;
      }
    }
  }

  #pragma unroll
  for (int i = 0; i < 4; ++i) {
    int row = row0 + 32 * i + rg;
    if (row < M) {
      #pragma unroll
      for (int q = 0; q < 4; ++q) {
        ushort4 v;
        v.x = f2bf(acc[i][q * 4 + 0]);
        v.y = f2bf(acc[i][q * 4 + 1]);
        v.z = f2bf(acc[i][q * 4 + 2]);
        v.w = f2bf(acc[i][q * 4 + 3]);
        *reinterpret_cast<ushort4*>(&C[(size_t)row * HD + cg * 4 + 32 * q]) = v;
      }
    }
  }
}

// ---------------- pull aggregation over bf16 rows, fused self-loop + bias + relu ----------------
// 32 lanes per node; lane reads 4 bf16 (8 B) per row; accumulate f32; output f32.
template <bool IND>
__global__ __launch_bounds__(256) void k_agg(const unsigned short* __restrict__ xw,
                                             const int* __restrict__ xidx,
                                             const int* __restrict__ rowptr,
                                             const uint2* __restrict__ csr,
                                             const float* __restrict__ dinv,
                                             const float* __restrict__ bias,
                                             float* __restrict__ outp) {
  int tid = blockIdx.x * blockDim.x + threadIdx.x;
  int n = tid >> 5, lane = tid & 31;
  if (n >= NN) return;
  int beg = rowptr[n], end = rowptr[n + 1];
  float4 acc = make_float4(0.f, 0.f, 0.f, 0.f);
  int e = beg;
  for (; e + 1 < end; e += 2) {        // unroll-2: two row loads in flight
    uint2 p0 = csr[e], p1 = csr[e + 1];
    int s0 = (int)p0.x, s1 = (int)p1.x;
    float c0 = __uint_as_float(p0.y), c1 = __uint_as_float(p1.y);
    if (IND) { s0 = xidx[s0]; s1 = xidx[s1]; }
    ushort4 u0 = reinterpret_cast<const ushort4*>(xw + (size_t)s0 * HD)[lane];
    ushort4 u1 = reinterpret_cast<const ushort4*>(xw + (size_t)s1 * HD)[lane];
    acc.x += c0 * bf2f(u0.x) + c1 * bf2f(u1.x);
    acc.y += c0 * bf2f(u0.y) + c1 * bf2f(u1.y);
    acc.z += c0 * bf2f(u0.z) + c1 * bf2f(u1.z);
    acc.w += c0 * bf2f(u0.w) + c1 * bf2f(u1.w);
  }
  if (e < end) {
    uint2 p0 = csr[e];
    int s0 = (int)p0.x;
    float c0 = __uint_as_float(p0.y);
    if (IND) s0 = xidx[s0];
    ushort4 u0 = reinterpret_cast<const ushort4*>(xw + (size_t)s0 * HD)[lane];
    acc.x += c0 * bf2f(u0.x); acc.y += c0 * bf2f(u0.y);
    acc.z += c0 * bf2f(u0.z); acc.w += c0 * bf2f(u0.w);
  }
  int sn = IND ? xidx[n] : n;
  float d = dinv[n];
  float cs = d * d;
  ushort4 us = reinterpret_cast<const ushort4*>(xw + (size_t)sn * HD)[lane];
  float4 bb = reinterpret_cast<const float4*>(bias)[lane];
  acc.x = fmaxf(acc.x + cs * bf2f(us.x) + bb.x, 0.f);
  acc.y = fmaxf(acc.y + cs * bf2f(us.y) + bb.y, 0.f);
  acc.z = fmaxf(acc.z + cs * bf2f(us.z) + bb.z, 0.f);
  acc.w = fmaxf(acc.w + cs * bf2f(us.w) + bb.w, 0.f);
  reinterpret_cast<float4*>(outp + (size_t)n * HD)[lane] = acc;
}

// ---------------- pooling ----------------
__global__ void k_zero(float* p, int n) {
  int i = blockIdx.x * blockDim.x + threadIdx.x;
  if (i < n) p[i] = 0.f;
}

__global__ void k_pool(const float* __restrict__ x, const int* __restrict__ batch,
                       float* __restrict__ sums) {
  int tid = blockIdx.x * blockDim.x + threadIdx.x;
  int g = tid >> 5, lane = tid & 31;
  int n0 = g * 8;
  if (n0 >= NN) return;
  int nend = min(n0 + 8, NN);
  float4 acc = make_float4(0.f, 0.f, 0.f, 0.f);
  int curb = batch[n0];
  for (int n = n0; n < nend; ++n) {
    int b = batch[n];
    if (b != curb) {
      float* o = sums + (size_t)curb * HD + lane * 4;
      atomicAdd(o + 0, acc.x); atomicAdd(o + 1, acc.y);
      atomicAdd(o + 2, acc.z); atomicAdd(o + 3, acc.w);
      acc = make_float4(0.f, 0.f, 0.f, 0.f);
      curb = b;
    }
    float4 v = reinterpret_cast<const float4*>(x + (size_t)n * HD)[lane];
    acc.x += v.x; acc.y += v.y; acc.z += v.z; acc.w += v.w;
  }
  float* o = sums + (size_t)curb * HD + lane * 4;
  atomicAdd(o + 0, acc.x); atomicAdd(o + 1, acc.y);
  atomicAdd(o + 2, acc.z); atomicAdd(o + 3, acc.w);
}

__global__ void k_counts(const int* __restrict__ batch, float* __restrict__ cnt) {
  int b = threadIdx.x;
  if (b >= NB) return;
  auto lb = [&](int v) {
    int lo = 0, hi = NN;
    while (lo < hi) { int m = (lo + hi) >> 1; if (batch[m] < v) lo = m + 1; else hi = m; }
    return lo;
  };
  cnt[b] = (float)(lb(b + 1) - lb(b));
}

// ---------------- MLP head + softmax ----------------
__global__ __launch_bounds__(64) void k_head(const float* __restrict__ sums,
                                             const float* __restrict__ cnt,
                                             const float* __restrict__ W1,
                                             const float* __restrict__ b1,
                                             const float* __restrict__ W2,
                                             const float* __restrict__ b2,
                                             float* __restrict__ out) {
  int g = blockIdx.x, t = threadIdx.x;  // 64 threads
  __shared__ float gv[128];
  __shared__ float h[64];
  __shared__ float logits[2];
  float c = fmaxf(cnt[g], 1.0f);
  gv[t] = sums[g * HD + t] / c;
  gv[t + 64] = sums[g * HD + 64 + t] / c;
  __syncthreads();
  float acc = b1[t];
  for (int k = 0; k < 128; ++k) acc += gv[k] * W1[k * 64 + t];
  h[t] = fmaxf(acc, 0.f);
  __syncthreads();
  if (t < 2) {
    float a = b2[t];
    for (int j = 0; j < 64; ++j) a += h[j] * W2[j * 2 + t];
    logits[t] = a;
  }
  __syncthreads();
  if (t < 2) {
    float m = fmaxf(logits[0], logits[1]);
    float e0 = __expf(logits[0] - m), e1 = __expf(logits[1] - m);
    out[g * 2 + t] = (t == 0 ? e0 : e1) / (e0 + e1);
  }
}

// ---------------- launch ----------------
extern "C" void kernel_launch(void* const* d_in, const int* in_sizes, int n_in,
                              void* d_out, int out_size, void* d_ws, size_t ws_size,
                              hipStream_t stream) {
  const int*   x_idx = (const int*)d_in[0];
  const int*   eidx  = (const int*)d_in[1];
  const float* ew    = (const float*)d_in[2];
  const int*   batch = (const int*)d_in[3];
  const float* emb   = (const float*)d_in[4];
  const float* W1    = (const float*)d_in[5];
  const float* b1    = (const float*)d_in[6];
  const float* W2    = (const float*)d_in[7];
  const float* b2    = (const float*)d_in[8];
  const float* mW1   = (const float*)d_in[9];
  const float* mb1   = (const float*)d_in[10];
  const float* mW2   = (const float*)d_in[11];
  const float* mb2   = (const float*)d_in[12];
  const int* src = eidx;
  const int* dst = eidx + NE;
  float* out = (float*)d_out;

  char* ws = (char*)d_ws;
  size_t off = 0;
  auto alloc = [&](size_t bytes) {
    void* p = ws + off;
    off += (bytes + 255) & ~(size_t)255;
    return p;
  };
  unsigned long long* packed = (unsigned long long*)alloc((size_t)NN * 8);
  float* dinv    = (float*)alloc((size_t)NN * 4);
  int*   part    = (int*)alloc((size_t)NN * 4);
  int*   bsum    = (int*)alloc((size_t)256 * 4);
  int*   rowptr  = (int*)alloc((size_t)(NN + 1) * 4);
  int*   cursor  = (int*)alloc((size_t)NN * 4);
  uint2* csr     = (uint2*)alloc((size_t)NE * 8);
  unsigned short* embW = (unsigned short*)alloc((size_t)NV * HD * 2);   // bf16
  unsigned short* bufA = (unsigned short*)alloc((size_t)NN * HD * 2);   // bf16
  float* bufB    = (float*)alloc((size_t)NN * HD * 4);
  float* sums    = (float*)alloc((size_t)NB * HD * 4);
  float* cnt     = (float*)alloc((size_t)NB * 4);

  // degree + in-degree histogram (single packed 64-bit atomic per edge)
  k_init<<<(NN + 255) / 256, 256, 0, stream>>>(packed);
  k_deg_hist<<<(NE + 255) / 256, 256, 0, stream>>>(dst, ew, packed);

  // CSR build: scan (computes dinv too) + fill (computes norm inline)
  k_scan_a<<<NBLK, 512, 0, stream>>>(packed, part, bsum, dinv);
  k_scan_b<<<1, 256, 0, stream>>>(bsum);
  k_scan_c<<<(NN + 255) / 256, 256, 0, stream>>>(part, bsum, rowptr, cursor);
  k_fill<<<(NE + 255) / 256, 256, 0, stream>>>(src, dst, ew, dinv, cursor, csr);

  // embW = bf16(emb_table @ W1)  (conv1's xW is a gather of embW)
  k_gemm128<<<(NV + 127) / 128, 256, 0, stream>>>(emb, W1, embW, NV);

  // conv1: bufB = relu(agg(embW[xidx]) + b1)   [f32 out]
  k_agg<true><<<(int)(((size_t)NN * 32 + 255) / 256), 256, 0, stream>>>(
      embW, x_idx, rowptr, csr, dinv, b1, bufB);

  // conv2: bufA = bf16(h1 @ W2) ; bufB = relu(agg(bufA) + b2)
  k_gemm128<<<(NN + 127) / 128, 256, 0, stream>>>(bufB, W2, bufA, NN);
  k_agg<false><<<(int)(((size_t)NN * 32 + 255) / 256), 256, 0, stream>>>(
      bufA, nullptr, rowptr, csr, dinv, b2, bufB);

  // pool + head
  k_zero<<<(NB * HD + 255) / 256, 256, 0, stream>>>(sums, NB * HD);
  k_pool<<<((NN + 7) / 8 * 32 + 255) / 256, 256, 0, stream>>>(bufB, batch, sums);
  k_counts<<<1, 128, 0, stream>>>(batch, cnt);
  k_head<<<NB, 64, 0, stream>>>(sums, cnt, mW1, mb1, mW2, mb2, out);
}

// Round 5
// 411.746 us; speedup vs baseline: 13.8757x; 1.1766x over previous
//
#include <hip/hip_runtime.h>
#include <hip/hip_bf16.h>

#define NN 100000      // nodes
#define NE 1600000     // edges
#define NB 128         // graphs
#define NV 10000       // vocab
#define HD 128         // emb = hid = 128
#define NBLK 196       // ceil(NN/512) for scan

#define FIX_SCALE 16777216.0f          // 2^24 fixed-point scale for edge weights
#define SUM_MASK  0xFFFFFFFFFFULL      // low 40 bits hold the weighted-degree sum

using bf16x8 = __attribute__((ext_vector_type(8))) short;
using f32x4  = __attribute__((ext_vector_type(4))) float;
typedef __attribute__((ext_vector_type(8))) unsigned short ushortv8;

__device__ __forceinline__ float bf2f(unsigned short b) {
  return __uint_as_float((unsigned)b << 16);
}
__device__ __forceinline__ unsigned short f2bf(float f) {
  __hip_bfloat16 h = __float2bfloat16(f);   // RNE
  return *reinterpret_cast<unsigned short*>(&h);
}

// ---------------- init packed deg/hist accumulator ----------------
__global__ void k_init(unsigned long long* packed) {
  int i = blockIdx.x * blockDim.x + threadIdx.x;
  if (i < NN) packed[i] = 0ULL;
}

// one 64-bit atomic per edge: count in bits [40,64), fixed-point ew sum in [0,40)
__global__ void k_deg_hist(const int* __restrict__ dst, const float* __restrict__ ew,
                           unsigned long long* __restrict__ packed) {
  int e = blockIdx.x * blockDim.x + threadIdx.x;
  if (e < NE) {
    unsigned long long fx = (unsigned long long)__float2uint_rn(ew[e] * FIX_SCALE);
    atomicAdd(&packed[dst[e]], (1ULL << 40) | fx);
  }
}

// ---------------- exclusive scan (3-phase) + dinv unpack ----------------
__global__ __launch_bounds__(512) void k_scan_a(const unsigned long long* __restrict__ packed,
                                                int* __restrict__ part,
                                                int* __restrict__ bsum,
                                                float* __restrict__ dinv) {
  __shared__ int sh[512];
  int t = threadIdx.x;
  int gid = blockIdx.x * 512 + t;
  unsigned long long p = (gid < NN) ? packed[gid] : 0ULL;
  int v = (int)(p >> 40);
  if (gid < NN)
    dinv[gid] = rsqrtf(1.0f + (float)(p & SUM_MASK) * (1.0f / FIX_SCALE));
  sh[t] = v;
  __syncthreads();
  #pragma unroll
  for (int off = 1; off < 512; off <<= 1) {
    int u = (t >= off) ? sh[t - off] : 0;
    __syncthreads();
    sh[t] += u;
    __syncthreads();
  }
  if (gid < NN) part[gid] = sh[t] - v;           // exclusive
  if (t == 511) bsum[blockIdx.x] = sh[511];      // block total
}

__global__ __launch_bounds__(256) void k_scan_b(int* __restrict__ bsum) {
  __shared__ int sh[256];
  int t = threadIdx.x;
  int v = (t < NBLK) ? bsum[t] : 0;
  sh[t] = v;
  __syncthreads();
  #pragma unroll
  for (int off = 1; off < 256; off <<= 1) {
    int u = (t >= off) ? sh[t - off] : 0;
    __syncthreads();
    sh[t] += u;
    __syncthreads();
  }
  if (t < NBLK) bsum[t] = sh[t] - v;             // exclusive block offsets
}

__global__ void k_scan_c(const int* __restrict__ part, const int* __restrict__ bsum,
                         int* __restrict__ rowptr, int* __restrict__ cursor) {
  int i = blockIdx.x * blockDim.x + threadIdx.x;
  if (i < NN) {
    int v = part[i] + bsum[i >> 9];
    rowptr[i] = v;
    cursor[i] = v;
  }
  if (i == 0) rowptr[NN] = NE;
}

// ---------------- CSR fill: packed (src, norm) in one 8B store ----------------
__global__ void k_fill(const int* __restrict__ src, const int* __restrict__ dst,
                       const float* __restrict__ ew, const float* __restrict__ dinv,
                       int* __restrict__ cursor, uint2* __restrict__ csr) {
  int e = blockIdx.x * blockDim.x + threadIdx.x;
  if (e < NE) {
    int s = src[e], d = dst[e];
    float nrm = dinv[s] * ew[e] * dinv[d];
    int pos = atomicAdd(&cursor[d], 1);
    csr[pos] = make_uint2((unsigned)s, __float_as_uint(nrm));
  }
}

// ---------------- W prep: Wt[n][k] = bf16(W[k][n]) ----------------
__global__ void k_wprep(const float* __restrict__ W, unsigned short* __restrict__ Wt) {
  int t = blockIdx.x * blockDim.x + threadIdx.x;  // 16384
  int k = t >> 7, n = t & 127;
  Wt[n * 128 + k] = f2bf(W[k * 128 + n]);
}

// ---------------- MFMA GEMM: C[M,128] = A[M,128] @ W[128,128], bf16 in/out ----------------
// 4 waves/block, BM=128: wave w owns rows [blk*128 + w*32, +32).
// Fragments (16x16x32 bf16): A[lane&15][(lane>>4)*8+j], B[(lane>>4)*8+j][lane&15]
//   -> B loaded from Wt (pre-transposed) as contiguous ushort8. C/D: col=lane&15,
//   row=(lane>>4)*4+reg (m89). C staged via LDS for ushort8 global stores.
template <bool AF32>
__global__ __launch_bounds__(256) void k_gemm_mfma(const void* __restrict__ Av,
                                                   const unsigned short* __restrict__ Wt,
                                                   unsigned short* __restrict__ C, int M) {
  __shared__ unsigned short Cs[128][136];
  const int t = threadIdx.x;
  const int wave = t >> 6, lane = t & 63;
  const int lrow = lane & 15, lk = lane >> 4;
  const int row0 = blockIdx.x * 128;
  const int wrow = row0 + wave * 32;

  f32x4 acc[2][8];
  #pragma unroll
  for (int i = 0; i < 2; ++i)
    #pragma unroll
    for (int j = 0; j < 8; ++j) acc[i][j] = (f32x4){0.f, 0.f, 0.f, 0.f};

  #pragma unroll
  for (int kt = 0; kt < 4; ++kt) {
    bf16x8 a[2];
    #pragma unroll
    for (int rt = 0; rt < 2; ++rt) {
      int r = wrow + rt * 16 + lrow;
      bf16x8 av = (bf16x8){0, 0, 0, 0, 0, 0, 0, 0};
      if (r < M) {
        if (AF32) {
          const float* ap = (const float*)Av + (size_t)r * HD + kt * 32 + lk * 8;
          #pragma unroll
          for (int j = 0; j < 8; ++j) av[j] = (short)f2bf(ap[j]);
        } else {
          av = *(const bf16x8*)((const unsigned short*)Av + (size_t)r * HD + kt * 32 + lk * 8);
        }
      }
      a[rt] = av;
    }
    #pragma unroll
    for (int ct = 0; ct < 8; ++ct) {
      bf16x8 b = *(const bf16x8*)(Wt + (size_t)(ct * 16 + lrow) * HD + kt * 32 + lk * 8);
      acc[0][ct] = __builtin_amdgcn_mfma_f32_16x16x32_bf16(a[0], b, acc[0][ct], 0, 0, 0);
      acc[1][ct] = __builtin_amdgcn_mfma_f32_16x16x32_bf16(a[1], b, acc[1][ct], 0, 0, 0);
    }
  }

  #pragma unroll
  for (int rt = 0; rt < 2; ++rt)
    #pragma unroll
    for (int ct = 0; ct < 8; ++ct)
      #pragma unroll
      for (int reg = 0; reg < 4; ++reg) {
        int lr = wave * 32 + rt * 16 + lk * 4 + reg;
        Cs[lr][ct * 16 + lrow] = f2bf(acc[rt][ct][reg]);
      }
  __syncthreads();

  #pragma unroll
  for (int i = 0; i < 8; ++i) {
    int idx = t + i * 256;       // 0..2047 ushort8 chunks
    int r = idx >> 4;
    int c = (idx & 15) * 8;
    int gr = row0 + r;
    if (gr < M)
      *(ushortv8*)(C + (size_t)gr * HD + c) = *(const ushortv8*)&Cs[r][c];
  }
}

// ---------------- pull aggregation over bf16 rows -> bf16 out, fused bias+relu ----------------
template <bool IND>
__global__ __launch_bounds__(256) void k_agg(const unsigned short* __restrict__ xw,
                                             const int* __restrict__ xidx,
                                             const int* __restrict__ rowptr,
                                             const uint2* __restrict__ csr,
                                             const float* __restrict__ dinv,
                                             const float* __restrict__ bias,
                                             unsigned short* __restrict__ outp) {
  int tid = blockIdx.x * blockDim.x + threadIdx.x;
  int n = tid >> 5, lane = tid & 31;
  if (n >= NN) return;
  int beg = rowptr[n], end = rowptr[n + 1];
  float4 acc = make_float4(0.f, 0.f, 0.f, 0.f);
  int e = beg;
  for (; e + 1 < end; e += 2) {        // unroll-2: two row loads in flight
    uint2 p0 = csr[e], p1 = csr[e + 1];
    int s0 = (int)p0.x, s1 = (int)p1.x;
    float c0 = __uint_as_float(p0.y), c1 = __uint_as_float(p1.y);
    if (IND) { s0 = xidx[s0]; s1 = xidx[s1]; }
    ushort4 u0 = reinterpret_cast<const ushort4*>(xw + (size_t)s0 * HD)[lane];
    ushort4 u1 = reinterpret_cast<const ushort4*>(xw + (size_t)s1 * HD)[lane];
    acc.x += c0 * bf2f(u0.x) + c1 * bf2f(u1.x);
    acc.y += c0 * bf2f(u0.y) + c1 * bf2f(u1.y);
    acc.z += c0 * bf2f(u0.z) + c1 * bf2f(u1.z);
    acc.w += c0 * bf2f(u0.w) + c1 * bf2f(u1.w);
  }
  if (e < end) {
    uint2 p0 = csr[e];
    int s0 = (int)p0.x;
    float c0 = __uint_as_float(p0.y);
    if (IND) s0 = xidx[s0];
    ushort4 u0 = reinterpret_cast<const ushort4*>(xw + (size_t)s0 * HD)[lane];
    acc.x += c0 * bf2f(u0.x); acc.y += c0 * bf2f(u0.y);
    acc.z += c0 * bf2f(u0.z); acc.w += c0 * bf2f(u0.w);
  }
  int sn = IND ? xidx[n] : n;
  float d = dinv[n];
  float cs = d * d;
  ushort4 us = reinterpret_cast<const ushort4*>(xw + (size_t)sn * HD)[lane];
  float4 bb = reinterpret_cast<const float4*>(bias)[lane];
  ushort4 r;
  r.x = f2bf(fmaxf(acc.x + cs * bf2f(us.x) + bb.x, 0.f));
  r.y = f2bf(fmaxf(acc.y + cs * bf2f(us.y) + bb.y, 0.f));
  r.z = f2bf(fmaxf(acc.z + cs * bf2f(us.z) + bb.z, 0.f));
  r.w = f2bf(fmaxf(acc.w + cs * bf2f(us.w) + bb.w, 0.f));
  reinterpret_cast<ushort4*>(outp + (size_t)n * HD)[lane] = r;
}

// ---------------- pooling ----------------
__global__ void k_zero(float* p, int n) {
  int i = blockIdx.x * blockDim.x + threadIdx.x;
  if (i < n) p[i] = 0.f;
}

__global__ void k_pool(const unsigned short* __restrict__ x, const int* __restrict__ batch,
                       float* __restrict__ sums) {
  int tid = blockIdx.x * blockDim.x + threadIdx.x;
  int g = tid >> 5, lane = tid & 31;
  int n0 = g * 8;
  if (n0 >= NN) return;
  int nend = min(n0 + 8, NN);
  float4 acc = make_float4(0.f, 0.f, 0.f, 0.f);
  int curb = batch[n0];
  for (int n = n0; n < nend; ++n) {
    int b = batch[n];
    if (b != curb) {
      float* o = sums + (size_t)curb * HD + lane * 4;
      atomicAdd(o + 0, acc.x); atomicAdd(o + 1, acc.y);
      atomicAdd(o + 2, acc.z); atomicAdd(o + 3, acc.w);
      acc = make_float4(0.f, 0.f, 0.f, 0.f);
      curb = b;
    }
    ushort4 v = reinterpret_cast<const ushort4*>(x + (size_t)n * HD)[lane];
    acc.x += bf2f(v.x); acc.y += bf2f(v.y);
    acc.z += bf2f(v.z); acc.w += bf2f(v.w);
  }
  float* o = sums + (size_t)curb * HD + lane * 4;
  atomicAdd(o + 0, acc.x); atomicAdd(o + 1, acc.y);
  atomicAdd(o + 2, acc.z); atomicAdd(o + 3, acc.w);
}

__global__ void k_counts(const int* __restrict__ batch, float* __restrict__ cnt) {
  int b = threadIdx.x;
  if (b >= NB) return;
  auto lb = [&](int v) {
    int lo = 0, hi = NN;
    while (lo < hi) { int m = (lo + hi) >> 1; if (batch[m] < v) lo = m + 1; else hi = m; }
    return lo;
  };
  cnt[b] = (float)(lb(b + 1) - lb(b));
}

// ---------------- MLP head + softmax ----------------
__global__ __launch_bounds__(64) void k_head(const float* __restrict__ sums,
                                             const float* __restrict__ cnt,
                                             const float* __restrict__ W1,
                                             const float* __restrict__ b1,
                                             const float* __restrict__ W2,
                                             const float* __restrict__ b2,
                                             float* __restrict__ out) {
  int g = blockIdx.x, t = threadIdx.x;  // 64 threads
  __shared__ float gv[128];
  __shared__ float h[64];
  __shared__ float logits[2];
  float c = fmaxf(cnt[g], 1.0f);
  gv[t] = sums[g * HD + t] / c;
  gv[t + 64] = sums[g * HD + 64 + t] / c;
  __syncthreads();
  float acc = b1[t];
  for (int k = 0; k < 128; ++k) acc += gv[k] * W1[k * 64 + t];
  h[t] = fmaxf(acc, 0.f);
  __syncthreads();
  if (t < 2) {
    float a = b2[t];
    for (int j = 0; j < 64; ++j) a += h[j] * W2[j * 2 + t];
    logits[t] = a;
  }
  __syncthreads();
  if (t < 2) {
    float m = fmaxf(logits[0], logits[1]);
    float e0 = __expf(logits[0] - m), e1 = __expf(logits[1] - m);
    out[g * 2 + t] = (t == 0 ? e0 : e1) / (e0 + e1);
  }
}

// ---------------- launch ----------------
extern "C" void kernel_launch(void* const* d_in, const int* in_sizes, int n_in,
                              void* d_out, int out_size, void* d_ws, size_t ws_size,
                              hipStream_t stream) {
  const int*   x_idx = (const int*)d_in[0];
  const int*   eidx  = (const int*)d_in[1];
  const float* ew    = (const float*)d_in[2];
  const int*   batch = (const int*)d_in[3];
  const float* emb   = (const float*)d_in[4];
  const float* W1    = (const float*)d_in[5];
  const float* b1    = (const float*)d_in[6];
  const float* W2    = (const float*)d_in[7];
  const float* b2    = (const float*)d_in[8];
  const float* mW1   = (const float*)d_in[9];
  const float* mb1   = (const float*)d_in[10];
  const float* mW2   = (const float*)d_in[11];
  const float* mb2   = (const float*)d_in[12];
  const int* src = eidx;
  const int* dst = eidx + NE;
  float* out = (float*)d_out;

  char* ws = (char*)d_ws;
  size_t off = 0;
  auto alloc = [&](size_t bytes) {
    void* p = ws + off;
    off += (bytes + 255) & ~(size_t)255;
    return p;
  };
  unsigned long long* packed = (unsigned long long*)alloc((size_t)NN * 8);
  float* dinv    = (float*)alloc((size_t)NN * 4);
  int*   part    = (int*)alloc((size_t)NN * 4);
  int*   bsum    = (int*)alloc((size_t)256 * 4);
  int*   rowptr  = (int*)alloc((size_t)(NN + 1) * 4);
  int*   cursor  = (int*)alloc((size_t)NN * 4);
  uint2* csr     = (uint2*)alloc((size_t)NE * 8);
  unsigned short* Wt1  = (unsigned short*)alloc((size_t)HD * HD * 2);
  unsigned short* Wt2  = (unsigned short*)alloc((size_t)HD * HD * 2);
  unsigned short* embW = (unsigned short*)alloc((size_t)NV * HD * 2);   // bf16
  unsigned short* bufA = (unsigned short*)alloc((size_t)NN * HD * 2);   // bf16
  unsigned short* bufB = (unsigned short*)alloc((size_t)NN * HD * 2);   // bf16
  float* sums    = (float*)alloc((size_t)NB * HD * 4);
  float* cnt     = (float*)alloc((size_t)NB * 4);

  // degree + in-degree histogram (single packed 64-bit atomic per edge)
  k_init<<<(NN + 255) / 256, 256, 0, stream>>>(packed);
  k_deg_hist<<<(NE + 255) / 256, 256, 0, stream>>>(dst, ew, packed);

  // CSR build: scan (computes dinv too) + fill (computes norm inline)
  k_scan_a<<<NBLK, 512, 0, stream>>>(packed, part, bsum, dinv);
  k_scan_b<<<1, 256, 0, stream>>>(bsum);
  k_scan_c<<<(NN + 255) / 256, 256, 0, stream>>>(part, bsum, rowptr, cursor);
  k_fill<<<(NE + 255) / 256, 256, 0, stream>>>(src, dst, ew, dinv, cursor, csr);

  // weight prep (transpose + bf16)
  k_wprep<<<64, 256, 0, stream>>>(W1, Wt1);
  k_wprep<<<64, 256, 0, stream>>>(W2, Wt2);

  // embW = bf16(emb_table @ W1)  (conv1's xW is a gather of embW)
  k_gemm_mfma<true><<<(NV + 127) / 128, 256, 0, stream>>>(emb, Wt1, embW, NV);

  // conv1: bufB = bf16(relu(agg(embW[xidx]) + b1))
  k_agg<true><<<(int)(((size_t)NN * 32 + 255) / 256), 256, 0, stream>>>(
      embW, x_idx, rowptr, csr, dinv, b1, bufB);

  // conv2: bufA = bf16(h1 @ W2) ; bufB = bf16(relu(agg(bufA) + b2))
  k_gemm_mfma<false><<<(NN + 127) / 128, 256, 0, stream>>>(bufB, Wt2, bufA, NN);
  k_agg<false><<<(int)(((size_t)NN * 32 + 255) / 256), 256, 0, stream>>>(
      bufA, nullptr, rowptr, csr, dinv, b2, bufB);

  // pool + head
  k_zero<<<(NB * HD + 255) / 256, 256, 0, stream>>>(sums, NB * HD);
  k_pool<<<((NN + 7) / 8 * 32 + 255) / 256, 256, 0, stream>>>(bufB, batch, sums);
  k_counts<<<1, 128, 0, stream>>>(batch, cnt);
  k_head<<<NB, 64, 0, stream>>>(sums, cnt, mW1, mb1, mW2, mb2, out);
}

// Round 6
// 342.986 us; speedup vs baseline: 16.6574x; 1.2005x over previous
//
#include <hip/hip_runtime.h>
#include <hip/hip_bf16.h>

#define NN 100000      // nodes
#define NE 1600000     // edges
#define NB 128         // graphs
#define NV 10000       // vocab
#define HD 128         // emb = hid = 128
#define NBLK 196       // ceil(NN/512) for scan

#define FIX_SCALE 16777216.0f          // 2^24 fixed-point scale for edge weights
#define SUM_MASK  0xFFFFFFFFFFULL      // low 40 bits hold the weighted-degree sum

using bf16x8 = __attribute__((ext_vector_type(8))) short;
using f32x4  = __attribute__((ext_vector_type(4))) float;
typedef __attribute__((ext_vector_type(8))) unsigned short ushortv8;

__device__ __forceinline__ float bf2f(unsigned short b) {
  return __uint_as_float((unsigned)b << 16);
}
__device__ __forceinline__ unsigned short f2bf(float f) {
  __hip_bfloat16 h = __float2bfloat16(f);   // RNE
  return *reinterpret_cast<unsigned short*>(&h);
}

// ---------------- init packed deg/hist accumulator ----------------
__global__ void k_init(unsigned long long* packed) {
  int i = blockIdx.x * blockDim.x + threadIdx.x;
  if (i < NN) packed[i] = 0ULL;
}

// one 64-bit atomic per edge: count in bits [40,64), fixed-point ew sum in [0,40).
// The returned OLD count is this edge's rank within its dst row -> no atomic in fill.
__global__ void k_deg_hist(const int* __restrict__ dst, const float* __restrict__ ew,
                           unsigned long long* __restrict__ packed,
                           int* __restrict__ rank) {
  int e = blockIdx.x * blockDim.x + threadIdx.x;
  if (e < NE) {
    unsigned long long fx = (unsigned long long)__float2uint_rn(ew[e] * FIX_SCALE);
    unsigned long long old = atomicAdd(&packed[dst[e]], (1ULL << 40) | fx);
    rank[e] = (int)(old >> 40);
  }
}

// ---------------- exclusive scan (3-phase) + dinv unpack ----------------
__global__ __launch_bounds__(512) void k_scan_a(const unsigned long long* __restrict__ packed,
                                                int* __restrict__ part,
                                                int* __restrict__ bsum,
                                                float* __restrict__ dinv) {
  __shared__ int sh[512];
  int t = threadIdx.x;
  int gid = blockIdx.x * 512 + t;
  unsigned long long p = (gid < NN) ? packed[gid] : 0ULL;
  int v = (int)(p >> 40);
  if (gid < NN)
    dinv[gid] = rsqrtf(1.0f + (float)(p & SUM_MASK) * (1.0f / FIX_SCALE));
  sh[t] = v;
  __syncthreads();
  #pragma unroll
  for (int off = 1; off < 512; off <<= 1) {
    int u = (t >= off) ? sh[t - off] : 0;
    __syncthreads();
    sh[t] += u;
    __syncthreads();
  }
  if (gid < NN) part[gid] = sh[t] - v;           // exclusive
  if (t == 511) bsum[blockIdx.x] = sh[511];      // block total
}

__global__ __launch_bounds__(256) void k_scan_b(int* __restrict__ bsum) {
  __shared__ int sh[256];
  int t = threadIdx.x;
  int v = (t < NBLK) ? bsum[t] : 0;
  sh[t] = v;
  __syncthreads();
  #pragma unroll
  for (int off = 1; off < 256; off <<= 1) {
    int u = (t >= off) ? sh[t - off] : 0;
    __syncthreads();
    sh[t] += u;
    __syncthreads();
  }
  if (t < NBLK) bsum[t] = sh[t] - v;             // exclusive block offsets
}

__global__ void k_scan_c(const int* __restrict__ part, const int* __restrict__ bsum,
                         int* __restrict__ rowptr) {
  int i = blockIdx.x * blockDim.x + threadIdx.x;
  if (i < NN) rowptr[i] = part[i] + bsum[i >> 9];
  if (i == 0) rowptr[NN] = NE;
}

// ---------------- CSR fill (atomic-free): pos = rowptr[dst] + rank ----------------
__global__ void k_fill(const int* __restrict__ src, const int* __restrict__ dst,
                       const float* __restrict__ ew, const float* __restrict__ dinv,
                       const int* __restrict__ rowptr, const int* __restrict__ rank,
                       uint2* __restrict__ csr) {
  int e = blockIdx.x * blockDim.x + threadIdx.x;
  if (e < NE) {
    int s = src[e], d = dst[e];
    float nrm = dinv[s] * ew[e] * dinv[d];
    int pos = rowptr[d] + rank[e];
    csr[pos] = make_uint2((unsigned)s, __float_as_uint(nrm));
  }
}

// ---------------- W prep: Wt[n][k] = bf16(W[k][n]) ----------------
__global__ void k_wprep(const float* __restrict__ W, unsigned short* __restrict__ Wt) {
  int t = blockIdx.x * blockDim.x + threadIdx.x;  // 16384
  int k = t >> 7, n = t & 127;
  Wt[n * 128 + k] = f2bf(W[k * 128 + n]);
}

// ---------------- MFMA GEMM: C[M,128] = A[M,128] @ W[128,128], bf16 in/out ----------------
template <bool AF32>
__global__ __launch_bounds__(256) void k_gemm_mfma(const void* __restrict__ Av,
                                                   const unsigned short* __restrict__ Wt,
                                                   unsigned short* __restrict__ C, int M) {
  __shared__ unsigned short Cs[128][136];
  const int t = threadIdx.x;
  const int wave = t >> 6, lane = t & 63;
  const int lrow = lane & 15, lk = lane >> 4;
  const int row0 = blockIdx.x * 128;
  const int wrow = row0 + wave * 32;

  f32x4 acc[2][8];
  #pragma unroll
  for (int i = 0; i < 2; ++i)
    #pragma unroll
    for (int j = 0; j < 8; ++j) acc[i][j] = (f32x4){0.f, 0.f, 0.f, 0.f};

  #pragma unroll
  for (int kt = 0; kt < 4; ++kt) {
    bf16x8 a[2];
    #pragma unroll
    for (int rt = 0; rt < 2; ++rt) {
      int r = wrow + rt * 16 + lrow;
      bf16x8 av = (bf16x8){0, 0, 0, 0, 0, 0, 0, 0};
      if (r < M) {
        if (AF32) {
          const float* ap = (const float*)Av + (size_t)r * HD + kt * 32 + lk * 8;
          #pragma unroll
          for (int j = 0; j < 8; ++j) av[j] = (short)f2bf(ap[j]);
        } else {
          av = *(const bf16x8*)((const unsigned short*)Av + (size_t)r * HD + kt * 32 + lk * 8);
        }
      }
      a[rt] = av;
    }
    #pragma unroll
    for (int ct = 0; ct < 8; ++ct) {
      bf16x8 b = *(const bf16x8*)(Wt + (size_t)(ct * 16 + lrow) * HD + kt * 32 + lk * 8);
      acc[0][ct] = __builtin_amdgcn_mfma_f32_16x16x32_bf16(a[0], b, acc[0][ct], 0, 0, 0);
      acc[1][ct] = __builtin_amdgcn_mfma_f32_16x16x32_bf16(a[1], b, acc[1][ct], 0, 0, 0);
    }
  }

  #pragma unroll
  for (int rt = 0; rt < 2; ++rt)
    #pragma unroll
    for (int ct = 0; ct < 8; ++ct)
      #pragma unroll
      for (int reg = 0; reg < 4; ++reg) {
        int lr = wave * 32 + rt * 16 + lk * 4 + reg;
        Cs[lr][ct * 16 + lrow] = f2bf(acc[rt][ct][reg]);
      }
  __syncthreads();

  #pragma unroll
  for (int i = 0; i < 8; ++i) {
    int idx = t + i * 256;       // 0..2047 ushort8 chunks
    int r = idx >> 4;
    int c = (idx & 15) * 8;
    int gr = row0 + r;
    if (gr < M)
      *(ushortv8*)(C + (size_t)gr * HD + c) = *(const ushortv8*)&Cs[r][c];
  }
}

// ---------------- pull aggregation over bf16 rows -> bf16 out, fused bias+relu ----------------
// 32 lanes/node, unroll-4 (4 row-gathers in flight per lane).
template <bool IND>
__global__ __launch_bounds__(256) void k_agg(const unsigned short* __restrict__ xw,
                                             const int* __restrict__ xidx,
                                             const int* __restrict__ rowptr,
                                             const uint2* __restrict__ csr,
                                             const float* __restrict__ dinv,
                                             const float* __restrict__ bias,
                                             unsigned short* __restrict__ outp) {
  int tid = blockIdx.x * blockDim.x + threadIdx.x;
  int n = tid >> 5, lane = tid & 31;
  if (n >= NN) return;
  int beg = rowptr[n], end = rowptr[n + 1];

  // issue self-row load early (in flight during edge loop)
  int sn = IND ? xidx[n] : n;
  ushort4 us = reinterpret_cast<const ushort4*>(xw + (size_t)sn * HD)[lane];

  float4 acc = make_float4(0.f, 0.f, 0.f, 0.f);
  int e = beg;
  for (; e + 3 < end; e += 4) {
    uint2 p0 = csr[e],     p1 = csr[e + 1];
    uint2 p2 = csr[e + 2], p3 = csr[e + 3];
    int s0 = (int)p0.x, s1 = (int)p1.x, s2 = (int)p2.x, s3 = (int)p3.x;
    if (IND) { s0 = xidx[s0]; s1 = xidx[s1]; s2 = xidx[s2]; s3 = xidx[s3]; }
    float c0 = __uint_as_float(p0.y), c1 = __uint_as_float(p1.y);
    float c2 = __uint_as_float(p2.y), c3 = __uint_as_float(p3.y);
    ushort4 u0 = reinterpret_cast<const ushort4*>(xw + (size_t)s0 * HD)[lane];
    ushort4 u1 = reinterpret_cast<const ushort4*>(xw + (size_t)s1 * HD)[lane];
    ushort4 u2 = reinterpret_cast<const ushort4*>(xw + (size_t)s2 * HD)[lane];
    ushort4 u3 = reinterpret_cast<const ushort4*>(xw + (size_t)s3 * HD)[lane];
    acc.x += c0 * bf2f(u0.x) + c1 * bf2f(u1.x) + c2 * bf2f(u2.x) + c3 * bf2f(u3.x);
    acc.y += c0 * bf2f(u0.y) + c1 * bf2f(u1.y) + c2 * bf2f(u2.y) + c3 * bf2f(u3.y);
    acc.z += c0 * bf2f(u0.z) + c1 * bf2f(u1.z) + c2 * bf2f(u2.z) + c3 * bf2f(u3.z);
    acc.w += c0 * bf2f(u0.w) + c1 * bf2f(u1.w) + c2 * bf2f(u2.w) + c3 * bf2f(u3.w);
  }
  for (; e < end; ++e) {
    uint2 p0 = csr[e];
    int s0 = (int)p0.x;
    float c0 = __uint_as_float(p0.y);
    if (IND) s0 = xidx[s0];
    ushort4 u0 = reinterpret_cast<const ushort4*>(xw + (size_t)s0 * HD)[lane];
    acc.x += c0 * bf2f(u0.x); acc.y += c0 * bf2f(u0.y);
    acc.z += c0 * bf2f(u0.z); acc.w += c0 * bf2f(u0.w);
  }
  float d = dinv[n];
  float cs = d * d;
  float4 bb = reinterpret_cast<const float4*>(bias)[lane];
  ushort4 r;
  r.x = f2bf(fmaxf(acc.x + cs * bf2f(us.x) + bb.x, 0.f));
  r.y = f2bf(fmaxf(acc.y + cs * bf2f(us.y) + bb.y, 0.f));
  r.z = f2bf(fmaxf(acc.z + cs * bf2f(us.z) + bb.z, 0.f));
  r.w = f2bf(fmaxf(acc.w + cs * bf2f(us.w) + bb.w, 0.f));
  reinterpret_cast<ushort4*>(outp + (size_t)n * HD)[lane] = r;
}

// ---------------- pooling ----------------
__global__ void k_zero(float* p, int n) {
  int i = blockIdx.x * blockDim.x + threadIdx.x;
  if (i < n) p[i] = 0.f;
}

__global__ void k_pool(const unsigned short* __restrict__ x, const int* __restrict__ batch,
                       float* __restrict__ sums) {
  int tid = blockIdx.x * blockDim.x + threadIdx.x;
  int g = tid >> 5, lane = tid & 31;
  int n0 = g * 8;
  if (n0 >= NN) return;
  int nend = min(n0 + 8, NN);
  float4 acc = make_float4(0.f, 0.f, 0.f, 0.f);
  int curb = batch[n0];
  for (int n = n0; n < nend; ++n) {
    int b = batch[n];
    if (b != curb) {
      float* o = sums + (size_t)curb * HD + lane * 4;
      atomicAdd(o + 0, acc.x); atomicAdd(o + 1, acc.y);
      atomicAdd(o + 2, acc.z); atomicAdd(o + 3, acc.w);
      acc = make_float4(0.f, 0.f, 0.f, 0.f);
      curb = b;
    }
    ushort4 v = reinterpret_cast<const ushort4*>(x + (size_t)n * HD)[lane];
    acc.x += bf2f(v.x); acc.y += bf2f(v.y);
    acc.z += bf2f(v.z); acc.w += bf2f(v.w);
  }
  float* o = sums + (size_t)curb * HD + lane * 4;
  atomicAdd(o + 0, acc.x); atomicAdd(o + 1, acc.y);
  atomicAdd(o + 2, acc.z); atomicAdd(o + 3, acc.w);
}

__global__ void k_counts(const int* __restrict__ batch, float* __restrict__ cnt) {
  int b = threadIdx.x;
  if (b >= NB) return;
  auto lb = [&](int v) {
    int lo = 0, hi = NN;
    while (lo < hi) { int m = (lo + hi) >> 1; if (batch[m] < v) lo = m + 1; else hi = m; }
    return lo;
  };
  cnt[b] = (float)(lb(b + 1) - lb(b));
}

// ---------------- MLP head + softmax ----------------
__global__ __launch_bounds__(64) void k_head(const float* __restrict__ sums,
                                             const float* __restrict__ cnt,
                                             const float* __restrict__ W1,
                                             const float* __restrict__ b1,
                                             const float* __restrict__ W2,
                                             const float* __restrict__ b2,
                                             float* __restrict__ out) {
  int g = blockIdx.x, t = threadIdx.x;  // 64 threads
  __shared__ float gv[128];
  __shared__ float h[64];
  __shared__ float logits[2];
  float c = fmaxf(cnt[g], 1.0f);
  gv[t] = sums[g * HD + t] / c;
  gv[t + 64] = sums[g * HD + 64 + t] / c;
  __syncthreads();
  float acc = b1[t];
  for (int k = 0; k < 128; ++k) acc += gv[k] * W1[k * 64 + t];
  h[t] = fmaxf(acc, 0.f);
  __syncthreads();
  if (t < 2) {
    float a = b2[t];
    for (int j = 0; j < 64; ++j) a += h[j] * W2[j * 2 + t];
    logits[t] = a;
  }
  __syncthreads();
  if (t < 2) {
    float m = fmaxf(logits[0], logits[1]);
    float e0 = __expf(logits[0] - m), e1 = __expf(logits[1] - m);
    out[g * 2 + t] = (t == 0 ? e0 : e1) / (e0 + e1);
  }
}

// ---------------- launch ----------------
extern "C" void kernel_launch(void* const* d_in, const int* in_sizes, int n_in,
                              void* d_out, int out_size, void* d_ws, size_t ws_size,
                              hipStream_t stream) {
  const int*   x_idx = (const int*)d_in[0];
  const int*   eidx  = (const int*)d_in[1];
  const float* ew    = (const float*)d_in[2];
  const int*   batch = (const int*)d_in[3];
  const float* emb   = (const float*)d_in[4];
  const float* W1    = (const float*)d_in[5];
  const float* b1    = (const float*)d_in[6];
  const float* W2    = (const float*)d_in[7];
  const float* b2    = (const float*)d_in[8];
  const float* mW1   = (const float*)d_in[9];
  const float* mb1   = (const float*)d_in[10];
  const float* mW2   = (const float*)d_in[11];
  const float* mb2   = (const float*)d_in[12];
  const int* src = eidx;
  const int* dst = eidx + NE;
  float* out = (float*)d_out;

  char* ws = (char*)d_ws;
  size_t off = 0;
  auto alloc = [&](size_t bytes) {
    void* p = ws + off;
    off += (bytes + 255) & ~(size_t)255;
    return p;
  };
  unsigned long long* packed = (unsigned long long*)alloc((size_t)NN * 8);
  float* dinv    = (float*)alloc((size_t)NN * 4);
  int*   part    = (int*)alloc((size_t)NN * 4);
  int*   bsum    = (int*)alloc((size_t)256 * 4);
  int*   rowptr  = (int*)alloc((size_t)(NN + 1) * 4);
  int*   rank    = (int*)alloc((size_t)NE * 4);
  uint2* csr     = (uint2*)alloc((size_t)NE * 8);
  unsigned short* Wt1  = (unsigned short*)alloc((size_t)HD * HD * 2);
  unsigned short* Wt2  = (unsigned short*)alloc((size_t)HD * HD * 2);
  unsigned short* embW = (unsigned short*)alloc((size_t)NV * HD * 2);   // bf16
  unsigned short* bufA = (unsigned short*)alloc((size_t)NN * HD * 2);   // bf16
  unsigned short* bufB = (unsigned short*)alloc((size_t)NN * HD * 2);   // bf16
  float* sums    = (float*)alloc((size_t)NB * HD * 4);
  float* cnt     = (float*)alloc((size_t)NB * 4);

  // degree + in-degree histogram + per-edge rank (single packed 64-bit atomic per edge)
  k_init<<<(NN + 255) / 256, 256, 0, stream>>>(packed);
  k_deg_hist<<<(NE + 255) / 256, 256, 0, stream>>>(dst, ew, packed, rank);

  // CSR build: scan (computes dinv too) + atomic-free fill (computes norm inline)
  k_scan_a<<<NBLK, 512, 0, stream>>>(packed, part, bsum, dinv);
  k_scan_b<<<1, 256, 0, stream>>>(bsum);
  k_scan_c<<<(NN + 255) / 256, 256, 0, stream>>>(part, bsum, rowptr);
  k_fill<<<(NE + 255) / 256, 256, 0, stream>>>(src, dst, ew, dinv, rowptr, rank, csr);

  // weight prep (transpose + bf16)
  k_wprep<<<64, 256, 0, stream>>>(W1, Wt1);
  k_wprep<<<64, 256, 0, stream>>>(W2, Wt2);

  // embW = bf16(emb_table @ W1)  (conv1's xW is a gather of embW)
  k_gemm_mfma<true><<<(NV + 127) / 128, 256, 0, stream>>>(emb, Wt1, embW, NV);

  // conv1: bufB = bf16(relu(agg(embW[xidx]) + b1))
  k_agg<true><<<(int)(((size_t)NN * 32 + 255) / 256), 256, 0, stream>>>(
      embW, x_idx, rowptr, csr, dinv, b1, bufB);

  // conv2: bufA = bf16(h1 @ W2) ; bufB = bf16(relu(agg(bufA) + b2))
  k_gemm_mfma<false><<<(NN + 127) / 128, 256, 0, stream>>>(bufB, Wt2, bufA, NN);
  k_agg<false><<<(int)(((size_t)NN * 32 + 255) / 256), 256, 0, stream>>>(
      bufA, nullptr, rowptr, csr, dinv, b2, bufB);

  // pool + head
  k_zero<<<(NB * HD + 255) / 256, 256, 0, stream>>>(sums, NB * HD);
  k_pool<<<((NN + 7) / 8 * 32 + 255) / 256, 256, 0, stream>>>(bufB, batch, sums);
  k_counts<<<1, 128, 0, stream>>>(batch, cnt);
  k_head<<<NB, 64, 0, stream>>>(sums, cnt, mW1, mb1, mW2, mb2, out);
}

// Round 7
// 304.833 us; speedup vs baseline: 18.7423x; 1.1252x over previous
//
#include <hip/hip_runtime.h>
#include <hip/hip_bf16.h>

#define NN 100000      // nodes
#define NE 1600000     // edges
#define NB 128         // graphs
#define NV 10000       // vocab
#define HD 128         // emb = hid = 128
#define NBLK 196       // ceil(NN/512) for scan

#define FIX_SCALE 16777216.0f          // 2^24 fixed-point scale for edge weights
#define SUM_MASK  0xFFFFFFFFFFULL      // low 40 bits hold the weighted-degree sum

using bf16x8 = __attribute__((ext_vector_type(8))) short;
using f32x4  = __attribute__((ext_vector_type(4))) float;
typedef __attribute__((ext_vector_type(8))) unsigned short ushortv8;
typedef __attribute__((ext_vector_type(8))) unsigned char ucharv8;
typedef float f32x2 __attribute__((ext_vector_type(2)));

__device__ __forceinline__ float bf2f(unsigned short b) {
  return __uint_as_float((unsigned)b << 16);
}
__device__ __forceinline__ unsigned short f2bf(float f) {
  __hip_bfloat16 h = __float2bfloat16(f);   // RNE
  return *reinterpret_cast<unsigned short*>(&h);
}
// f32 -> fp8 e4m3 (OCP on gfx950), single value -> low byte
__device__ __forceinline__ unsigned char f2fp8(float f) {
  return (unsigned char)(__builtin_amdgcn_cvt_pk_fp8_f32(f, 0.f, 0, false) & 0xff);
}

// ---------------- init packed deg/hist accumulator ----------------
__global__ void k_init(unsigned long long* packed) {
  int i = blockIdx.x * blockDim.x + threadIdx.x;
  if (i < NN) packed[i] = 0ULL;
}

// one 64-bit atomic per edge: count in bits [40,64), fixed-point ew sum in [0,40).
// The returned OLD count is this edge's rank within its dst row -> no atomic in fill.
__global__ void k_deg_hist(const int* __restrict__ dst, const float* __restrict__ ew,
                           unsigned long long* __restrict__ packed,
                           int* __restrict__ rank) {
  int e = blockIdx.x * blockDim.x + threadIdx.x;
  if (e < NE) {
    unsigned long long fx = (unsigned long long)__float2uint_rn(ew[e] * FIX_SCALE);
    unsigned long long old = atomicAdd(&packed[dst[e]], (1ULL << 40) | fx);
    rank[e] = (int)(old >> 40);
  }
}

// ---------------- exclusive scan (3-phase) + dinv unpack ----------------
__global__ __launch_bounds__(512) void k_scan_a(const unsigned long long* __restrict__ packed,
                                                int* __restrict__ part,
                                                int* __restrict__ bsum,
                                                float* __restrict__ dinv) {
  __shared__ int sh[512];
  int t = threadIdx.x;
  int gid = blockIdx.x * 512 + t;
  unsigned long long p = (gid < NN) ? packed[gid] : 0ULL;
  int v = (int)(p >> 40);
  if (gid < NN)
    dinv[gid] = rsqrtf(1.0f + (float)(p & SUM_MASK) * (1.0f / FIX_SCALE));
  sh[t] = v;
  __syncthreads();
  #pragma unroll
  for (int off = 1; off < 512; off <<= 1) {
    int u = (t >= off) ? sh[t - off] : 0;
    __syncthreads();
    sh[t] += u;
    __syncthreads();
  }
  if (gid < NN) part[gid] = sh[t] - v;           // exclusive
  if (t == 511) bsum[blockIdx.x] = sh[511];      // block total
}

__global__ __launch_bounds__(256) void k_scan_b(int* __restrict__ bsum) {
  __shared__ int sh[256];
  int t = threadIdx.x;
  int v = (t < NBLK) ? bsum[t] : 0;
  sh[t] = v;
  __syncthreads();
  #pragma unroll
  for (int off = 1; off < 256; off <<= 1) {
    int u = (t >= off) ? sh[t - off] : 0;
    __syncthreads();
    sh[t] += u;
    __syncthreads();
  }
  if (t < NBLK) bsum[t] = sh[t] - v;             // exclusive block offsets
}

__global__ void k_scan_c(const int* __restrict__ part, const int* __restrict__ bsum,
                         int* __restrict__ rowptr) {
  int i = blockIdx.x * blockDim.x + threadIdx.x;
  if (i < NN) rowptr[i] = part[i] + bsum[i >> 9];
  if (i == 0) rowptr[NN] = NE;
}

// ---------------- CSR fill (atomic-free): pos = rowptr[dst] + rank ----------------
__global__ void k_fill(const int* __restrict__ src, const int* __restrict__ dst,
                       const float* __restrict__ ew, const float* __restrict__ dinv,
                       const int* __restrict__ rowptr, const int* __restrict__ rank,
                       uint2* __restrict__ csr) {
  int e = blockIdx.x * blockDim.x + threadIdx.x;
  if (e < NE) {
    int s = src[e], d = dst[e];
    float nrm = dinv[s] * ew[e] * dinv[d];
    int pos = rowptr[d] + rank[e];
    csr[pos] = make_uint2((unsigned)s, __float_as_uint(nrm));
  }
}

// ---------------- W prep: Wt[n][k] = bf16(W[k][n]) ----------------
__global__ void k_wprep(const float* __restrict__ W, unsigned short* __restrict__ Wt) {
  int t = blockIdx.x * blockDim.x + threadIdx.x;  // 16384
  int k = t >> 7, n = t & 127;
  Wt[n * 128 + k] = f2bf(W[k * 128 + n]);
}

// ---------------- MFMA GEMM: C[M,128] = A[M,128] @ W[128,128], out fp8 ----------------
// 4 waves/block, BM=128. Fragments per m89 layout; C staged via LDS (bytes) for
// 8B coalesced global stores.
template <bool AF32>
__global__ __launch_bounds__(256) void k_gemm_mfma(const void* __restrict__ Av,
                                                   const unsigned short* __restrict__ Wt,
                                                   unsigned char* __restrict__ C, int M) {
  __shared__ unsigned char Cs[128][132];
  const int t = threadIdx.x;
  const int wave = t >> 6, lane = t & 63;
  const int lrow = lane & 15, lk = lane >> 4;
  const int row0 = blockIdx.x * 128;
  const int wrow = row0 + wave * 32;

  f32x4 acc[2][8];
  #pragma unroll
  for (int i = 0; i < 2; ++i)
    #pragma unroll
    for (int j = 0; j < 8; ++j) acc[i][j] = (f32x4){0.f, 0.f, 0.f, 0.f};

  #pragma unroll
  for (int kt = 0; kt < 4; ++kt) {
    bf16x8 a[2];
    #pragma unroll
    for (int rt = 0; rt < 2; ++rt) {
      int r = wrow + rt * 16 + lrow;
      bf16x8 av = (bf16x8){0, 0, 0, 0, 0, 0, 0, 0};
      if (r < M) {
        if (AF32) {
          const float* ap = (const float*)Av + (size_t)r * HD + kt * 32 + lk * 8;
          #pragma unroll
          for (int j = 0; j < 8; ++j) av[j] = (short)f2bf(ap[j]);
        } else {
          av = *(const bf16x8*)((const unsigned short*)Av + (size_t)r * HD + kt * 32 + lk * 8);
        }
      }
      a[rt] = av;
    }
    #pragma unroll
    for (int ct = 0; ct < 8; ++ct) {
      bf16x8 b = *(const bf16x8*)(Wt + (size_t)(ct * 16 + lrow) * HD + kt * 32 + lk * 8);
      acc[0][ct] = __builtin_amdgcn_mfma_f32_16x16x32_bf16(a[0], b, acc[0][ct], 0, 0, 0);
      acc[1][ct] = __builtin_amdgcn_mfma_f32_16x16x32_bf16(a[1], b, acc[1][ct], 0, 0, 0);
    }
  }

  #pragma unroll
  for (int rt = 0; rt < 2; ++rt)
    #pragma unroll
    for (int ct = 0; ct < 8; ++ct)
      #pragma unroll
      for (int reg = 0; reg < 4; ++reg) {
        int lr = wave * 32 + rt * 16 + lk * 4 + reg;
        Cs[lr][ct * 16 + lrow] = f2fp8(acc[rt][ct][reg]);
      }
  __syncthreads();

  #pragma unroll
  for (int i = 0; i < 8; ++i) {
    int idx = t + i * 256;       // 0..2047 uchar8 chunks
    int r = idx >> 4;
    int c = (idx & 15) * 8;
    int gr = row0 + r;
    if (gr < M)
      *(ucharv8*)(C + (size_t)gr * HD + c) = *(const ucharv8*)&Cs[r][c];
  }
}

// ---------------- pull aggregation over fp8 rows -> bf16 out, fused bias+relu ----------------
// 32 lanes/node, lane covers 4 columns (4B/row); unroll-4 keeps 4 gathers in flight.
template <bool IND>
__global__ __launch_bounds__(256) void k_agg(const unsigned char* __restrict__ xw,
                                             const int* __restrict__ xidx,
                                             const int* __restrict__ rowptr,
                                             const uint2* __restrict__ csr,
                                             const float* __restrict__ dinv,
                                             const float* __restrict__ bias,
                                             unsigned short* __restrict__ outp) {
  int tid = blockIdx.x * blockDim.x + threadIdx.x;
  int n = tid >> 5, lane = tid & 31;
  if (n >= NN) return;
  int beg = rowptr[n], end = rowptr[n + 1];

  // issue self-row load early (in flight during edge loop)
  int sn = IND ? xidx[n] : n;
  unsigned uself = *(const unsigned*)(xw + (size_t)sn * HD + lane * 4);

  float4 acc = make_float4(0.f, 0.f, 0.f, 0.f);
  int e = beg;
  for (; e + 3 < end; e += 4) {
    uint2 p0 = csr[e],     p1 = csr[e + 1];
    uint2 p2 = csr[e + 2], p3 = csr[e + 3];
    int s0 = (int)p0.x, s1 = (int)p1.x, s2 = (int)p2.x, s3 = (int)p3.x;
    if (IND) { s0 = xidx[s0]; s1 = xidx[s1]; s2 = xidx[s2]; s3 = xidx[s3]; }
    float c0 = __uint_as_float(p0.y), c1 = __uint_as_float(p1.y);
    float c2 = __uint_as_float(p2.y), c3 = __uint_as_float(p3.y);
    unsigned u0 = *(const unsigned*)(xw + (size_t)s0 * HD + lane * 4);
    unsigned u1 = *(const unsigned*)(xw + (size_t)s1 * HD + lane * 4);
    unsigned u2 = *(const unsigned*)(xw + (size_t)s2 * HD + lane * 4);
    unsigned u3 = *(const unsigned*)(xw + (size_t)s3 * HD + lane * 4);
    f32x2 l0 = __builtin_amdgcn_cvt_pk_f32_fp8((int)u0, false);
    f32x2 h0 = __builtin_amdgcn_cvt_pk_f32_fp8((int)u0, true);
    f32x2 l1 = __builtin_amdgcn_cvt_pk_f32_fp8((int)u1, false);
    f32x2 h1 = __builtin_amdgcn_cvt_pk_f32_fp8((int)u1, true);
    f32x2 l2 = __builtin_amdgcn_cvt_pk_f32_fp8((int)u2, false);
    f32x2 h2 = __builtin_amdgcn_cvt_pk_f32_fp8((int)u2, true);
    f32x2 l3 = __builtin_amdgcn_cvt_pk_f32_fp8((int)u3, false);
    f32x2 h3 = __builtin_amdgcn_cvt_pk_f32_fp8((int)u3, true);
    acc.x += c0 * l0[0] + c1 * l1[0] + c2 * l2[0] + c3 * l3[0];
    acc.y += c0 * l0[1] + c1 * l1[1] + c2 * l2[1] + c3 * l3[1];
    acc.z += c0 * h0[0] + c1 * h1[0] + c2 * h2[0] + c3 * h3[0];
    acc.w += c0 * h0[1] + c1 * h1[1] + c2 * h2[1] + c3 * h3[1];
  }
  for (; e < end; ++e) {
    uint2 p0 = csr[e];
    int s0 = (int)p0.x;
    float c0 = __uint_as_float(p0.y);
    if (IND) s0 = xidx[s0];
    unsigned u0 = *(const unsigned*)(xw + (size_t)s0 * HD + lane * 4);
    f32x2 l0 = __builtin_amdgcn_cvt_pk_f32_fp8((int)u0, false);
    f32x2 h0 = __builtin_amdgcn_cvt_pk_f32_fp8((int)u0, true);
    acc.x += c0 * l0[0]; acc.y += c0 * l0[1];
    acc.z += c0 * h0[0]; acc.w += c0 * h0[1];
  }
  float d = dinv[n];
  float cs = d * d;
  f32x2 sl = __builtin_amdgcn_cvt_pk_f32_fp8((int)uself, false);
  f32x2 sh = __builtin_amdgcn_cvt_pk_f32_fp8((int)uself, true);
  float4 bb = reinterpret_cast<const float4*>(bias)[lane];
  ushort4 r;
  r.x = f2bf(fmaxf(acc.x + cs * sl[0] + bb.x, 0.f));
  r.y = f2bf(fmaxf(acc.y + cs * sl[1] + bb.y, 0.f));
  r.z = f2bf(fmaxf(acc.z + cs * sh[0] + bb.z, 0.f));
  r.w = f2bf(fmaxf(acc.w + cs * sh[1] + bb.w, 0.f));
  reinterpret_cast<ushort4*>(outp + (size_t)n * HD)[lane] = r;
}

// ---------------- pooling ----------------
// zero sums (all 64 blocks) + counts (block 0, 128 threads) in one launch
__global__ __launch_bounds__(256) void k_zero_counts(float* __restrict__ sums,
                                                     const int* __restrict__ batch,
                                                     float* __restrict__ cnt) {
  int i = blockIdx.x * blockDim.x + threadIdx.x;
  if (i < NB * HD) sums[i] = 0.f;
  if (blockIdx.x == 0 && threadIdx.x < NB) {
    int b = threadIdx.x;
    auto lb = [&](int v) {
      int lo = 0, hi = NN;
      while (lo < hi) { int m = (lo + hi) >> 1; if (batch[m] < v) lo = m + 1; else hi = m; }
      return lo;
    };
    cnt[b] = (float)(lb(b + 1) - lb(b));
  }
}

__global__ void k_pool(const unsigned short* __restrict__ x, const int* __restrict__ batch,
                       float* __restrict__ sums) {
  int tid = blockIdx.x * blockDim.x + threadIdx.x;
  int g = tid >> 5, lane = tid & 31;
  int n0 = g * 8;
  if (n0 >= NN) return;
  int nend = min(n0 + 8, NN);
  float4 acc = make_float4(0.f, 0.f, 0.f, 0.f);
  int curb = batch[n0];
  for (int n = n0; n < nend; ++n) {
    int b = batch[n];
    if (b != curb) {
      float* o = sums + (size_t)curb * HD + lane * 4;
      atomicAdd(o + 0, acc.x); atomicAdd(o + 1, acc.y);
      atomicAdd(o + 2, acc.z); atomicAdd(o + 3, acc.w);
      acc = make_float4(0.f, 0.f, 0.f, 0.f);
      curb = b;
    }
    ushort4 v = reinterpret_cast<const ushort4*>(x + (size_t)n * HD)[lane];
    acc.x += bf2f(v.x); acc.y += bf2f(v.y);
    acc.z += bf2f(v.z); acc.w += bf2f(v.w);
  }
  float* o = sums + (size_t)curb * HD + lane * 4;
  atomicAdd(o + 0, acc.x); atomicAdd(o + 1, acc.y);
  atomicAdd(o + 2, acc.z); atomicAdd(o + 3, acc.w);
}

// ---------------- MLP head + softmax ----------------
__global__ __launch_bounds__(64) void k_head(const float* __restrict__ sums,
                                             const float* __restrict__ cnt,
                                             const float* __restrict__ W1,
                                             const float* __restrict__ b1,
                                             const float* __restrict__ W2,
                                             const float* __restrict__ b2,
                                             float* __restrict__ out) {
  int g = blockIdx.x, t = threadIdx.x;  // 64 threads
  __shared__ float gv[128];
  __shared__ float h[64];
  __shared__ float logits[2];
  float c = fmaxf(cnt[g], 1.0f);
  gv[t] = sums[g * HD + t] / c;
  gv[t + 64] = sums[g * HD + 64 + t] / c;
  __syncthreads();
  float acc = b1[t];
  for (int k = 0; k < 128; ++k) acc += gv[k] * W1[k * 64 + t];
  h[t] = fmaxf(acc, 0.f);
  __syncthreads();
  if (t < 2) {
    float a = b2[t];
    for (int j = 0; j < 64; ++j) a += h[j] * W2[j * 2 + t];
    logits[t] = a;
  }
  __syncthreads();
  if (t < 2) {
    float m = fmaxf(logits[0], logits[1]);
    float e0 = __expf(logits[0] - m), e1 = __expf(logits[1] - m);
    out[g * 2 + t] = (t == 0 ? e0 : e1) / (e0 + e1);
  }
}

// ---------------- launch ----------------
extern "C" void kernel_launch(void* const* d_in, const int* in_sizes, int n_in,
                              void* d_out, int out_size, void* d_ws, size_t ws_size,
                              hipStream_t stream) {
  const int*   x_idx = (const int*)d_in[0];
  const int*   eidx  = (const int*)d_in[1];
  const float* ew    = (const float*)d_in[2];
  const int*   batch = (const int*)d_in[3];
  const float* emb   = (const float*)d_in[4];
  const float* W1    = (const float*)d_in[5];
  const float* b1    = (const float*)d_in[6];
  const float* W2    = (const float*)d_in[7];
  const float* b2    = (const float*)d_in[8];
  const float* mW1   = (const float*)d_in[9];
  const float* mb1   = (const float*)d_in[10];
  const float* mW2   = (const float*)d_in[11];
  const float* mb2   = (const float*)d_in[12];
  const int* src = eidx;
  const int* dst = eidx + NE;
  float* out = (float*)d_out;

  char* ws = (char*)d_ws;
  size_t off = 0;
  auto alloc = [&](size_t bytes) {
    void* p = ws + off;
    off += (bytes + 255) & ~(size_t)255;
    return p;
  };
  unsigned long long* packed = (unsigned long long*)alloc((size_t)NN * 8);
  float* dinv    = (float*)alloc((size_t)NN * 4);
  int*   part    = (int*)alloc((size_t)NN * 4);
  int*   bsum    = (int*)alloc((size_t)256 * 4);
  int*   rowptr  = (int*)alloc((size_t)(NN + 1) * 4);
  int*   rank    = (int*)alloc((size_t)NE * 4);
  uint2* csr     = (uint2*)alloc((size_t)NE * 8);
  unsigned short* Wt1  = (unsigned short*)alloc((size_t)HD * HD * 2);
  unsigned short* Wt2  = (unsigned short*)alloc((size_t)HD * HD * 2);
  unsigned char* embW = (unsigned char*)alloc((size_t)NV * HD);        // fp8
  unsigned char* bufA = (unsigned char*)alloc((size_t)NN * HD);        // fp8
  unsigned short* bufB = (unsigned short*)alloc((size_t)NN * HD * 2);  // bf16
  float* sums    = (float*)alloc((size_t)NB * HD * 4);
  float* cnt     = (float*)alloc((size_t)NB * 4);

  // degree + in-degree histogram + per-edge rank (single packed 64-bit atomic per edge)
  k_init<<<(NN + 255) / 256, 256, 0, stream>>>(packed);
  k_deg_hist<<<(NE + 255) / 256, 256, 0, stream>>>(dst, ew, packed, rank);

  // CSR build: scan (computes dinv too) + atomic-free fill (computes norm inline)
  k_scan_a<<<NBLK, 512, 0, stream>>>(packed, part, bsum, dinv);
  k_scan_b<<<1, 256, 0, stream>>>(bsum);
  k_scan_c<<<(NN + 255) / 256, 256, 0, stream>>>(part, bsum, rowptr);
  k_fill<<<(NE + 255) / 256, 256, 0, stream>>>(src, dst, ew, dinv, rowptr, rank, csr);

  // weight prep (transpose + bf16)
  k_wprep<<<64, 256, 0, stream>>>(W1, Wt1);
  k_wprep<<<64, 256, 0, stream>>>(W2, Wt2);

  // embW = fp8(emb_table @ W1)  (conv1's xW is a gather of embW)
  k_gemm_mfma<true><<<(NV + 127) / 128, 256, 0, stream>>>(emb, Wt1, embW, NV);

  // conv1: bufB = bf16(relu(agg(embW[xidx]) + b1))
  k_agg<true><<<(int)(((size_t)NN * 32 + 255) / 256), 256, 0, stream>>>(
      embW, x_idx, rowptr, csr, dinv, b1, bufB);

  // conv2: bufA = fp8(h1 @ W2) ; bufB = bf16(relu(agg(bufA) + b2))
  k_gemm_mfma<false><<<(NN + 127) / 128, 256, 0, stream>>>(bufB, Wt2, bufA, NN);
  k_agg<false><<<(int)(((size_t)NN * 32 + 255) / 256), 256, 0, stream>>>(
      bufA, nullptr, rowptr, csr, dinv, b2, bufB);

  // pool + head
  k_zero_counts<<<64, 256, 0, stream>>>(sums, batch, cnt);
  k_pool<<<((NN + 7) / 8 * 32 + 255) / 256, 256, 0, stream>>>(bufB, batch, sums);
  k_head<<<NB, 64, 0, stream>>>(sums, cnt, mW1, mb1, mW2, mb2, out);
}

// Round 8
// 262.209 us; speedup vs baseline: 21.7890x; 1.1626x over previous
//
#include <hip/hip_runtime.h>
#include <hip/hip_bf16.h>

#define NN 100000      // nodes
#define NE 1600000     // edges
#define NB 128         // graphs
#define NV 10000       // vocab
#define HD 128         // emb = hid = 128

#define NBUCK 391      // ceil(NN/256) buckets, bucket = dst >> 8
#define EBLK 256       // edge blocks for bucket passes
#define EPB (NE / EBLK)  // 6250 edges per block (exact)

using bf16x8 = __attribute__((ext_vector_type(8))) short;
using f32x4  = __attribute__((ext_vector_type(4))) float;
typedef __attribute__((ext_vector_type(8))) unsigned short ushortv8;
typedef __attribute__((ext_vector_type(8))) unsigned char ucharv8;
typedef float f32x2 __attribute__((ext_vector_type(2)));

__device__ __forceinline__ float bf2f(unsigned short b) {
  return __uint_as_float((unsigned)b << 16);
}
__device__ __forceinline__ unsigned short f2bf(float f) {
  __hip_bfloat16 h = __float2bfloat16(f);   // RNE
  return *reinterpret_cast<unsigned short*>(&h);
}
// f32 -> fp8 e4m3 (OCP on gfx950), single value -> low byte
__device__ __forceinline__ unsigned char f2fp8(float f) {
  return (unsigned char)(__builtin_amdgcn_cvt_pk_fp8_f32(f, 0.f, 0, false) & 0xff);
}

// ============ bucketed counting-sort CSR build (no global atomics) ============

// Pass A: per-block bucket histogram (LDS atomics only)
__global__ __launch_bounds__(256) void k_bcount(const int* __restrict__ dst,
                                                int* __restrict__ cntmat) {
  __shared__ int h[NBUCK];
  int t = threadIdx.x, blk = blockIdx.x;
  for (int i = t; i < NBUCK; i += 256) h[i] = 0;
  __syncthreads();
  int base = blk * EPB;
  for (int i = t; i < EPB; i += 256) atomicAdd(&h[dst[base + i] >> 8], 1);
  __syncthreads();
  for (int i = t; i < NBUCK; i += 256) cntmat[blk * NBUCK + i] = h[i];
}

// Column scan: for bucket bu, exclusive prefix over blocks; totals out.
__global__ __launch_bounds__(256) void k_cscan(int* __restrict__ cntmat,
                                               int* __restrict__ totals) {
  __shared__ int sh[256];
  int bu = blockIdx.x, t = threadIdx.x;
  int v = cntmat[t * NBUCK + bu];
  sh[t] = v;
  __syncthreads();
  #pragma unroll
  for (int off = 1; off < 256; off <<= 1) {
    int u = (t >= off) ? sh[t - off] : 0;
    __syncthreads();
    sh[t] += u;
    __syncthreads();
  }
  cntmat[t * NBUCK + bu] = sh[t] - v;   // exclusive over blocks
  if (t == 255) totals[bu] = sh[255];
}

// Bucket-total scan -> bucketBase[0..NBUCK], bucketBase[NBUCK] = NE
__global__ __launch_bounds__(512) void k_tscan(const int* __restrict__ totals,
                                               int* __restrict__ bucketBase) {
  __shared__ int sh[512];
  int t = threadIdx.x;
  int v = (t < NBUCK) ? totals[t] : 0;
  sh[t] = v;
  __syncthreads();
  #pragma unroll
  for (int off = 1; off < 512; off <<= 1) {
    int u = (t >= off) ? sh[t - off] : 0;
    __syncthreads();
    sh[t] += u;
    __syncthreads();
  }
  if (t < NBUCK) bucketBase[t] = sh[t] - v;
  if (t == NBUCK - 1) bucketBase[NBUCK] = sh[t];   // = NE
}

// Pass B: scatter edges into bucket-sorted arrays (LDS cursor atomics)
__global__ __launch_bounds__(256) void k_bscatter(const int* __restrict__ src,
                                                  const int* __restrict__ dst,
                                                  const float* __restrict__ ew,
                                                  const int* __restrict__ cntmat,
                                                  const int* __restrict__ bucketBase,
                                                  int* __restrict__ sdst,
                                                  uint2* __restrict__ spair) {
  __shared__ int off[NBUCK];
  int t = threadIdx.x, blk = blockIdx.x;
  for (int i = t; i < NBUCK; i += 256)
    off[i] = bucketBase[i] + cntmat[blk * NBUCK + i];
  __syncthreads();
  int base = blk * EPB;
  for (int i = t; i < EPB; i += 256) {
    int e = base + i;
    int d = dst[e];
    int pos = atomicAdd(&off[d >> 8], 1);
    sdst[pos] = d;
    spair[pos] = make_uint2((unsigned)src[e], __float_as_uint(ew[e]));
  }
}

// Pass C1: per-bucket node degree/weighted-sum -> rowptr, dinv (all local)
__global__ __launch_bounds__(256) void k_bdeg(const int* __restrict__ sdst,
                                              const uint2* __restrict__ spair,
                                              const int* __restrict__ bucketBase,
                                              int* __restrict__ rowptr,
                                              float* __restrict__ dinv) {
  __shared__ int cnt[256];
  __shared__ float ws[256];
  __shared__ int sh[256];
  int bu = blockIdx.x, t = threadIdx.x;
  cnt[t] = 0; ws[t] = 0.f;
  __syncthreads();
  int ebeg = bucketBase[bu], eend = bucketBase[bu + 1];
  for (int e = ebeg + t; e < eend; e += 256) {
    int dl = sdst[e] & 255;
    atomicAdd(&cnt[dl], 1);
    atomicAdd(&ws[dl], __uint_as_float(spair[e].y));
  }
  __syncthreads();
  int v = cnt[t];
  sh[t] = v;
  __syncthreads();
  #pragma unroll
  for (int off = 1; off < 256; off <<= 1) {
    int u = (t >= off) ? sh[t - off] : 0;
    __syncthreads();
    sh[t] += u;
    __syncthreads();
  }
  int gid = bu * 256 + t;
  if (gid < NN) {
    rowptr[gid] = ebeg + sh[t] - v;
    dinv[gid] = rsqrtf(1.0f + ws[t]);
  }
  if (gid == NN) rowptr[NN] = NE;   // bu=390, t=160 exists (NBUCK*256 > NN)
}

// Pass C2: per-bucket CSR fill with norm (LDS rank atomics)
__global__ __launch_bounds__(256) void k_bfill(const int* __restrict__ sdst,
                                               const uint2* __restrict__ spair,
                                               const int* __restrict__ bucketBase,
                                               const int* __restrict__ rowptr,
                                               const float* __restrict__ dinv,
                                               uint2* __restrict__ csr) {
  __shared__ int cnt[256];
  int bu = blockIdx.x, t = threadIdx.x;
  cnt[t] = 0;
  __syncthreads();
  int ebeg = bucketBase[bu], eend = bucketBase[bu + 1];
  for (int e = ebeg + t; e < eend; e += 256) {
    int d = sdst[e];
    uint2 p = spair[e];
    int r = atomicAdd(&cnt[d & 255], 1);
    float nrm = dinv[(int)p.x] * __uint_as_float(p.y) * dinv[d];
    csr[rowptr[d] + r] = make_uint2(p.x, __float_as_uint(nrm));
  }
}

// ---------------- W prep: both weights in one launch ----------------
__global__ void k_wprep2(const float* __restrict__ W1, const float* __restrict__ W2,
                         unsigned short* __restrict__ Wt1, unsigned short* __restrict__ Wt2) {
  int t = blockIdx.x * blockDim.x + threadIdx.x;  // 32768
  const float* W = (t < 16384) ? W1 : W2;
  unsigned short* Wt = (t < 16384) ? Wt1 : Wt2;
  int i = t & 16383;
  int k = i >> 7, n = i & 127;
  Wt[n * 128 + k] = f2bf(W[k * 128 + n]);
}

// ---------------- MFMA GEMM: C[M,128] = A[M,128] @ W[128,128], out fp8 ----------------
template <bool AF32>
__global__ __launch_bounds__(256) void k_gemm_mfma(const void* __restrict__ Av,
                                                   const unsigned short* __restrict__ Wt,
                                                   unsigned char* __restrict__ C, int M) {
  __shared__ unsigned char Cs[128][132];
  const int t = threadIdx.x;
  const int wave = t >> 6, lane = t & 63;
  const int lrow = lane & 15, lk = lane >> 4;
  const int row0 = blockIdx.x * 128;
  const int wrow = row0 + wave * 32;

  f32x4 acc[2][8];
  #pragma unroll
  for (int i = 0; i < 2; ++i)
    #pragma unroll
    for (int j = 0; j < 8; ++j) acc[i][j] = (f32x4){0.f, 0.f, 0.f, 0.f};

  #pragma unroll
  for (int kt = 0; kt < 4; ++kt) {
    bf16x8 a[2];
    #pragma unroll
    for (int rt = 0; rt < 2; ++rt) {
      int r = wrow + rt * 16 + lrow;
      bf16x8 av = (bf16x8){0, 0, 0, 0, 0, 0, 0, 0};
      if (r < M) {
        if (AF32) {
          const float* ap = (const float*)Av + (size_t)r * HD + kt * 32 + lk * 8;
          #pragma unroll
          for (int j = 0; j < 8; ++j) av[j] = (short)f2bf(ap[j]);
        } else {
          av = *(const bf16x8*)((const unsigned short*)Av + (size_t)r * HD + kt * 32 + lk * 8);
        }
      }
      a[rt] = av;
    }
    #pragma unroll
    for (int ct = 0; ct < 8; ++ct) {
      bf16x8 b = *(const bf16x8*)(Wt + (size_t)(ct * 16 + lrow) * HD + kt * 32 + lk * 8);
      acc[0][ct] = __builtin_amdgcn_mfma_f32_16x16x32_bf16(a[0], b, acc[0][ct], 0, 0, 0);
      acc[1][ct] = __builtin_amdgcn_mfma_f32_16x16x32_bf16(a[1], b, acc[1][ct], 0, 0, 0);
    }
  }

  #pragma unroll
  for (int rt = 0; rt < 2; ++rt)
    #pragma unroll
    for (int ct = 0; ct < 8; ++ct)
      #pragma unroll
      for (int reg = 0; reg < 4; ++reg) {
        int lr = wave * 32 + rt * 16 + lk * 4 + reg;
        Cs[lr][ct * 16 + lrow] = f2fp8(acc[rt][ct][reg]);
      }
  __syncthreads();

  #pragma unroll
  for (int i = 0; i < 8; ++i) {
    int idx = t + i * 256;       // 0..2047 uchar8 chunks
    int r = idx >> 4;
    int c = (idx & 15) * 8;
    int gr = row0 + r;
    if (gr < M)
      *(ucharv8*)(C + (size_t)gr * HD + c) = *(const ucharv8*)&Cs[r][c];
  }
}

// ---------------- pull aggregation over fp8 rows -> bf16 out, fused bias+relu ----------------
template <bool IND>
__global__ __launch_bounds__(256) void k_agg(const unsigned char* __restrict__ xw,
                                             const int* __restrict__ xidx,
                                             const int* __restrict__ rowptr,
                                             const uint2* __restrict__ csr,
                                             const float* __restrict__ dinv,
                                             const float* __restrict__ bias,
                                             unsigned short* __restrict__ outp) {
  int tid = blockIdx.x * blockDim.x + threadIdx.x;
  int n = tid >> 5, lane = tid & 31;
  if (n >= NN) return;
  int beg = rowptr[n], end = rowptr[n + 1];

  int sn = IND ? xidx[n] : n;
  unsigned uself = *(const unsigned*)(xw + (size_t)sn * HD + lane * 4);

  float4 acc = make_float4(0.f, 0.f, 0.f, 0.f);
  int e = beg;
  for (; e + 3 < end; e += 4) {
    uint2 p0 = csr[e],     p1 = csr[e + 1];
    uint2 p2 = csr[e + 2], p3 = csr[e + 3];
    int s0 = (int)p0.x, s1 = (int)p1.x, s2 = (int)p2.x, s3 = (int)p3.x;
    if (IND) { s0 = xidx[s0]; s1 = xidx[s1]; s2 = xidx[s2]; s3 = xidx[s3]; }
    float c0 = __uint_as_float(p0.y), c1 = __uint_as_float(p1.y);
    float c2 = __uint_as_float(p2.y), c3 = __uint_as_float(p3.y);
    unsigned u0 = *(const unsigned*)(xw + (size_t)s0 * HD + lane * 4);
    unsigned u1 = *(const unsigned*)(xw + (size_t)s1 * HD + lane * 4);
    unsigned u2 = *(const unsigned*)(xw + (size_t)s2 * HD + lane * 4);
    unsigned u3 = *(const unsigned*)(xw + (size_t)s3 * HD + lane * 4);
    f32x2 l0 = __builtin_amdgcn_cvt_pk_f32_fp8((int)u0, false);
    f32x2 h0 = __builtin_amdgcn_cvt_pk_f32_fp8((int)u0, true);
    f32x2 l1 = __builtin_amdgcn_cvt_pk_f32_fp8((int)u1, false);
    f32x2 h1 = __builtin_amdgcn_cvt_pk_f32_fp8((int)u1, true);
    f32x2 l2 = __builtin_amdgcn_cvt_pk_f32_fp8((int)u2, false);
    f32x2 h2 = __builtin_amdgcn_cvt_pk_f32_fp8((int)u2, true);
    f32x2 l3 = __builtin_amdgcn_cvt_pk_f32_fp8((int)u3, false);
    f32x2 h3 = __builtin_amdgcn_cvt_pk_f32_fp8((int)u3, true);
    acc.x += c0 * l0[0] + c1 * l1[0] + c2 * l2[0] + c3 * l3[0];
    acc.y += c0 * l0[1] + c1 * l1[1] + c2 * l2[1] + c3 * l3[1];
    acc.z += c0 * h0[0] + c1 * h1[0] + c2 * h2[0] + c3 * h3[0];
    acc.w += c0 * h0[1] + c1 * h1[1] + c2 * h2[1] + c3 * h3[1];
  }
  for (; e < end; ++e) {
    uint2 p0 = csr[e];
    int s0 = (int)p0.x;
    float c0 = __uint_as_float(p0.y);
    if (IND) s0 = xidx[s0];
    unsigned u0 = *(const unsigned*)(xw + (size_t)s0 * HD + lane * 4);
    f32x2 l0 = __builtin_amdgcn_cvt_pk_f32_fp8((int)u0, false);
    f32x2 h0 = __builtin_amdgcn_cvt_pk_f32_fp8((int)u0, true);
    acc.x += c0 * l0[0]; acc.y += c0 * l0[1];
    acc.z += c0 * h0[0]; acc.w += c0 * h0[1];
  }
  float d = dinv[n];
  float cs = d * d;
  f32x2 sl = __builtin_amdgcn_cvt_pk_f32_fp8((int)uself, false);
  f32x2 sh = __builtin_amdgcn_cvt_pk_f32_fp8((int)uself, true);
  float4 bb = reinterpret_cast<const float4*>(bias)[lane];
  ushort4 r;
  r.x = f2bf(fmaxf(acc.x + cs * sl[0] + bb.x, 0.f));
  r.y = f2bf(fmaxf(acc.y + cs * sl[1] + bb.y, 0.f));
  r.z = f2bf(fmaxf(acc.z + cs * sh[0] + bb.z, 0.f));
  r.w = f2bf(fmaxf(acc.w + cs * sh[1] + bb.w, 0.f));
  reinterpret_cast<ushort4*>(outp + (size_t)n * HD)[lane] = r;
}

// ---------------- pooling ----------------
__global__ __launch_bounds__(256) void k_zero_counts(float* __restrict__ sums,
                                                     const int* __restrict__ batch,
                                                     float* __restrict__ cnt) {
  int i = blockIdx.x * blockDim.x + threadIdx.x;
  if (i < NB * HD) sums[i] = 0.f;
  if (blockIdx.x == 0 && threadIdx.x < NB) {
    int b = threadIdx.x;
    auto lb = [&](int v) {
      int lo = 0, hi = NN;
      while (lo < hi) { int m = (lo + hi) >> 1; if (batch[m] < v) lo = m + 1; else hi = m; }
      return lo;
    };
    cnt[b] = (float)(lb(b + 1) - lb(b));
  }
}

__global__ void k_pool(const unsigned short* __restrict__ x, const int* __restrict__ batch,
                       float* __restrict__ sums) {
  int tid = blockIdx.x * blockDim.x + threadIdx.x;
  int g = tid >> 5, lane = tid & 31;
  int n0 = g * 8;
  if (n0 >= NN) return;
  int nend = min(n0 + 8, NN);
  float4 acc = make_float4(0.f, 0.f, 0.f, 0.f);
  int curb = batch[n0];
  for (int n = n0; n < nend; ++n) {
    int b = batch[n];
    if (b != curb) {
      float* o = sums + (size_t)curb * HD + lane * 4;
      atomicAdd(o + 0, acc.x); atomicAdd(o + 1, acc.y);
      atomicAdd(o + 2, acc.z); atomicAdd(o + 3, acc.w);
      acc = make_float4(0.f, 0.f, 0.f, 0.f);
      curb = b;
    }
    ushort4 v = reinterpret_cast<const ushort4*>(x + (size_t)n * HD)[lane];
    acc.x += bf2f(v.x); acc.y += bf2f(v.y);
    acc.z += bf2f(v.z); acc.w += bf2f(v.w);
  }
  float* o = sums + (size_t)curb * HD + lane * 4;
  atomicAdd(o + 0, acc.x); atomicAdd(o + 1, acc.y);
  atomicAdd(o + 2, acc.z); atomicAdd(o + 3, acc.w);
}

// ---------------- MLP head + softmax ----------------
__global__ __launch_bounds__(64) void k_head(const float* __restrict__ sums,
                                             const float* __restrict__ cnt,
                                             const float* __restrict__ W1,
                                             const float* __restrict__ b1,
                                             const float* __restrict__ W2,
                                             const float* __restrict__ b2,
                                             float* __restrict__ out) {
  int g = blockIdx.x, t = threadIdx.x;  // 64 threads
  __shared__ float gv[128];
  __shared__ float h[64];
  __shared__ float logits[2];
  float c = fmaxf(cnt[g], 1.0f);
  gv[t] = sums[g * HD + t] / c;
  gv[t + 64] = sums[g * HD + 64 + t] / c;
  __syncthreads();
  float acc = b1[t];
  for (int k = 0; k < 128; ++k) acc += gv[k] * W1[k * 64 + t];
  h[t] = fmaxf(acc, 0.f);
  __syncthreads();
  if (t < 2) {
    float a = b2[t];
    for (int j = 0; j < 64; ++j) a += h[j] * W2[j * 2 + t];
    logits[t] = a;
  }
  __syncthreads();
  if (t < 2) {
    float m = fmaxf(logits[0], logits[1]);
    float e0 = __expf(logits[0] - m), e1 = __expf(logits[1] - m);
    out[g * 2 + t] = (t == 0 ? e0 : e1) / (e0 + e1);
  }
}

// ---------------- launch ----------------
extern "C" void kernel_launch(void* const* d_in, const int* in_sizes, int n_in,
                              void* d_out, int out_size, void* d_ws, size_t ws_size,
                              hipStream_t stream) {
  const int*   x_idx = (const int*)d_in[0];
  const int*   eidx  = (const int*)d_in[1];
  const float* ew    = (const float*)d_in[2];
  const int*   batch = (const int*)d_in[3];
  const float* emb   = (const float*)d_in[4];
  const float* W1    = (const float*)d_in[5];
  const float* b1    = (const float*)d_in[6];
  const float* W2    = (const float*)d_in[7];
  const float* b2    = (const float*)d_in[8];
  const float* mW1   = (const float*)d_in[9];
  const float* mb1   = (const float*)d_in[10];
  const float* mW2   = (const float*)d_in[11];
  const float* mb2   = (const float*)d_in[12];
  const int* src = eidx;
  const int* dst = eidx + NE;
  float* out = (float*)d_out;

  char* ws = (char*)d_ws;
  size_t off = 0;
  auto alloc = [&](size_t bytes) {
    void* p = ws + off;
    off += (bytes + 255) & ~(size_t)255;
    return p;
  };
  int*   cntmat     = (int*)alloc((size_t)EBLK * NBUCK * 4);
  int*   totals     = (int*)alloc((size_t)NBUCK * 4);
  int*   bucketBase = (int*)alloc((size_t)(NBUCK + 1) * 4);
  int*   rowptr     = (int*)alloc((size_t)(NN + 1) * 4);
  float* dinv       = (float*)alloc((size_t)NN * 4);
  uint2* csr        = (uint2*)alloc((size_t)NE * 8);
  unsigned short* Wt1  = (unsigned short*)alloc((size_t)HD * HD * 2);
  unsigned short* Wt2  = (unsigned short*)alloc((size_t)HD * HD * 2);
  unsigned char* embW  = (unsigned char*)alloc((size_t)NV * HD);        // fp8
  unsigned char* bufA  = (unsigned char*)alloc((size_t)NN * HD);        // fp8
  float* sums    = (float*)alloc((size_t)NB * HD * 4);
  float* cnt     = (float*)alloc((size_t)NB * 4);
  // union region: bucket-sorted edge arrays live only until k_bfill; bufB
  // (bf16 activations) is first written by k_agg<true> afterwards.
  char* unionReg = (char*)alloc((size_t)NN * HD * 2);   // 25.6 MB >= 19.2 MB
  int*   sdst  = (int*)unionReg;
  uint2* spair = (uint2*)(unionReg + (size_t)NE * 4);
  unsigned short* bufB = (unsigned short*)unionReg;

  // ---- CSR build via bucketed counting sort (zero global atomics) ----
  k_bcount<<<EBLK, 256, 0, stream>>>(dst, cntmat);
  k_cscan<<<NBUCK, 256, 0, stream>>>(cntmat, totals);
  k_tscan<<<1, 512, 0, stream>>>(totals, bucketBase);
  k_bscatter<<<EBLK, 256, 0, stream>>>(src, dst, ew, cntmat, bucketBase, sdst, spair);
  k_bdeg<<<NBUCK, 256, 0, stream>>>(sdst, spair, bucketBase, rowptr, dinv);
  k_bfill<<<NBUCK, 256, 0, stream>>>(sdst, spair, bucketBase, rowptr, dinv, csr);

  // weight prep (transpose + bf16, both weights in one launch)
  k_wprep2<<<128, 256, 0, stream>>>(W1, W2, Wt1, Wt2);

  // embW = fp8(emb_table @ W1)  (conv1's xW is a gather of embW)
  k_gemm_mfma<true><<<(NV + 127) / 128, 256, 0, stream>>>(emb, Wt1, embW, NV);

  // conv1: bufB = bf16(relu(agg(embW[xidx]) + b1))
  k_agg<true><<<(int)(((size_t)NN * 32 + 255) / 256), 256, 0, stream>>>(
      embW, x_idx, rowptr, csr, dinv, b1, bufB);

  // conv2: bufA = fp8(h1 @ W2) ; bufB = bf16(relu(agg(bufA) + b2))
  k_gemm_mfma<false><<<(NN + 127) / 128, 256, 0, stream>>>(bufB, Wt2, bufA, NN);
  k_agg<false><<<(int)(((size_t)NN * 32 + 255) / 256), 256, 0, stream>>>(
      bufA, nullptr, rowptr, csr, dinv, b2, bufB);

  // pool + head
  k_zero_counts<<<64, 256, 0, stream>>>(sums, batch, cnt);
  k_pool<<<((NN + 7) / 8 * 32 + 255) / 256, 256, 0, stream>>>(bufB, batch, sums);
  k_head<<<NB, 64, 0, stream>>>(sums, cnt, mW1, mb1, mW2, mb2, out);
}

// Round 9
// 196.545 us; speedup vs baseline: 29.0684x; 1.3341x over previous
//
#include <hip/hip_runtime.h>
#include <hip/hip_bf16.h>

#define NN 100000      // nodes
#define NE 1600000     // edges
#define NB 128         // graphs
#define NV 10000       // vocab
#define HD 128         // emb = hid = 128

#define NBUCK 391      // ceil(NN/256) buckets, bucket = dst >> 8
#define EBLK 256       // edge blocks for bucket passes
#define EPB (NE / EBLK)  // 6250 edges per block (exact)

using bf16x8 = __attribute__((ext_vector_type(8))) short;
using f32x4  = __attribute__((ext_vector_type(4))) float;
typedef __attribute__((ext_vector_type(8))) unsigned short ushortv8;
typedef __attribute__((ext_vector_type(8))) unsigned char ucharv8;
typedef float f32x2 __attribute__((ext_vector_type(2)));

__device__ __forceinline__ float bf2f(unsigned short b) {
  return __uint_as_float((unsigned)b << 16);
}
__device__ __forceinline__ unsigned short f2bf(float f) {
  __hip_bfloat16 h = __float2bfloat16(f);   // RNE
  return *reinterpret_cast<unsigned short*>(&h);
}
// f32 -> fp8 e4m3 (OCP on gfx950), single value -> low byte
__device__ __forceinline__ unsigned char f2fp8(float f) {
  return (unsigned char)(__builtin_amdgcn_cvt_pk_fp8_f32(f, 0.f, 0, false) & 0xff);
}
// acc[0..15] += c * fp8x16(u)
__device__ __forceinline__ void acc16(float* acc, uint4 u, float c) {
  f32x2 v;
  v = __builtin_amdgcn_cvt_pk_f32_fp8((int)u.x, false); acc[0] += c*v[0]; acc[1] += c*v[1];
  v = __builtin_amdgcn_cvt_pk_f32_fp8((int)u.x, true);  acc[2] += c*v[0]; acc[3] += c*v[1];
  v = __builtin_amdgcn_cvt_pk_f32_fp8((int)u.y, false); acc[4] += c*v[0]; acc[5] += c*v[1];
  v = __builtin_amdgcn_cvt_pk_f32_fp8((int)u.y, true);  acc[6] += c*v[0]; acc[7] += c*v[1];
  v = __builtin_amdgcn_cvt_pk_f32_fp8((int)u.z, false); acc[8] += c*v[0]; acc[9] += c*v[1];
  v = __builtin_amdgcn_cvt_pk_f32_fp8((int)u.z, true);  acc[10]+= c*v[0]; acc[11]+= c*v[1];
  v = __builtin_amdgcn_cvt_pk_f32_fp8((int)u.w, false); acc[12]+= c*v[0]; acc[13]+= c*v[1];
  v = __builtin_amdgcn_cvt_pk_f32_fp8((int)u.w, true);  acc[14]+= c*v[0]; acc[15]+= c*v[1];
}

// ============ bucketed counting-sort CSR build (no global atomics) ============

__global__ __launch_bounds__(256) void k_bcount(const int* __restrict__ dst,
                                                int* __restrict__ cntmat) {
  __shared__ int h[NBUCK];
  int t = threadIdx.x, blk = blockIdx.x;
  for (int i = t; i < NBUCK; i += 256) h[i] = 0;
  __syncthreads();
  int base = blk * EPB;
  for (int i = t; i < EPB; i += 256) atomicAdd(&h[dst[base + i] >> 8], 1);
  __syncthreads();
  for (int i = t; i < NBUCK; i += 256) cntmat[blk * NBUCK + i] = h[i];
}

__global__ __launch_bounds__(256) void k_cscan(int* __restrict__ cntmat,
                                               int* __restrict__ totals) {
  __shared__ int sh[256];
  int bu = blockIdx.x, t = threadIdx.x;
  int v = cntmat[t * NBUCK + bu];
  sh[t] = v;
  __syncthreads();
  #pragma unroll
  for (int off = 1; off < 256; off <<= 1) {
    int u = (t >= off) ? sh[t - off] : 0;
    __syncthreads();
    sh[t] += u;
    __syncthreads();
  }
  cntmat[t * NBUCK + bu] = sh[t] - v;   // exclusive over blocks
  if (t == 255) totals[bu] = sh[255];
}

__global__ __launch_bounds__(512) void k_tscan(const int* __restrict__ totals,
                                               int* __restrict__ bucketBase) {
  __shared__ int sh[512];
  int t = threadIdx.x;
  int v = (t < NBUCK) ? totals[t] : 0;
  sh[t] = v;
  __syncthreads();
  #pragma unroll
  for (int off = 1; off < 512; off <<= 1) {
    int u = (t >= off) ? sh[t - off] : 0;
    __syncthreads();
    sh[t] += u;
    __syncthreads();
  }
  if (t < NBUCK) bucketBase[t] = sh[t] - v;
  if (t == NBUCK - 1) bucketBase[NBUCK] = sh[t];   // = NE
}

__global__ __launch_bounds__(256) void k_bscatter(const int* __restrict__ src,
                                                  const int* __restrict__ dst,
                                                  const float* __restrict__ ew,
                                                  const int* __restrict__ cntmat,
                                                  const int* __restrict__ bucketBase,
                                                  unsigned char* __restrict__ dloc,
                                                  uint2* __restrict__ spair) {
  __shared__ int off[NBUCK];
  int t = threadIdx.x, blk = blockIdx.x;
  for (int i = t; i < NBUCK; i += 256)
    off[i] = bucketBase[i] + cntmat[blk * NBUCK + i];
  __syncthreads();
  int base = blk * EPB;
  for (int i = t; i < EPB; i += 256) {
    int e = base + i;
    int d = dst[e];
    int pos = atomicAdd(&off[d >> 8], 1);
    dloc[pos] = (unsigned char)(d & 255);
    spair[pos] = make_uint2((unsigned)src[e], __float_as_uint(ew[e]));
  }
}

__global__ __launch_bounds__(256) void k_bdeg(const unsigned char* __restrict__ dloc,
                                              const uint2* __restrict__ spair,
                                              const int* __restrict__ bucketBase,
                                              int* __restrict__ rowptr,
                                              float* __restrict__ dinv) {
  __shared__ int cnt[256];
  __shared__ float ws[256];
  __shared__ int sh[256];
  int bu = blockIdx.x, t = threadIdx.x;
  cnt[t] = 0; ws[t] = 0.f;
  __syncthreads();
  int ebeg = bucketBase[bu], eend = bucketBase[bu + 1];
  for (int e = ebeg + t; e < eend; e += 256) {
    int dl = dloc[e];
    atomicAdd(&cnt[dl], 1);
    atomicAdd(&ws[dl], __uint_as_float(spair[e].y));
  }
  __syncthreads();
  int v = cnt[t];
  sh[t] = v;
  __syncthreads();
  #pragma unroll
  for (int off = 1; off < 256; off <<= 1) {
    int u = (t >= off) ? sh[t - off] : 0;
    __syncthreads();
    sh[t] += u;
    __syncthreads();
  }
  int gid = bu * 256 + t;
  if (gid < NN) {
    rowptr[gid] = ebeg + sh[t] - v;
    dinv[gid] = rsqrtf(1.0f + ws[t]);
  }
  if (gid == NN) rowptr[NN] = NE;
}

__global__ __launch_bounds__(256) void k_bfill(const unsigned char* __restrict__ dloc,
                                               const uint2* __restrict__ spair,
                                               const int* __restrict__ bucketBase,
                                               const int* __restrict__ rowptr,
                                               const float* __restrict__ dinv,
                                               uint2* __restrict__ csr) {
  __shared__ int cnt[256];
  __shared__ float sdv[256];
  __shared__ int srp[256];
  int bu = blockIdx.x, t = threadIdx.x;
  cnt[t] = 0;
  int gid = (bu << 8) + t;
  if (gid < NN) { sdv[t] = dinv[gid]; srp[t] = rowptr[gid]; }
  __syncthreads();
  int ebeg = bucketBase[bu], eend = bucketBase[bu + 1];
  for (int e = ebeg + t; e < eend; e += 256) {
    int dl = dloc[e];
    uint2 p = spair[e];
    int r = atomicAdd(&cnt[dl], 1);
    float nrm = dinv[(int)p.x] * __uint_as_float(p.y) * sdv[dl];
    csr[srp[dl] + r] = make_uint2(p.x, __float_as_uint(nrm));
  }
}

// ---------------- W prep: both weights in one launch ----------------
__global__ void k_wprep2(const float* __restrict__ W1, const float* __restrict__ W2,
                         unsigned short* __restrict__ Wt1, unsigned short* __restrict__ Wt2) {
  int t = blockIdx.x * blockDim.x + threadIdx.x;  // 32768
  const float* W = (t < 16384) ? W1 : W2;
  unsigned short* Wt = (t < 16384) ? Wt1 : Wt2;
  int i = t & 16383;
  int k = i >> 7, n = i & 127;
  Wt[n * 128 + k] = f2bf(W[k * 128 + n]);
}

// ---------------- MFMA GEMM: C[M,128] = A[M,128] @ W[128,128], out fp8 ----------------
template <bool AF32>
__global__ __launch_bounds__(256) void k_gemm_mfma(const void* __restrict__ Av,
                                                   const unsigned short* __restrict__ Wt,
                                                   unsigned char* __restrict__ C, int M) {
  __shared__ unsigned char Cs[128][132];
  const int t = threadIdx.x;
  const int wave = t >> 6, lane = t & 63;
  const int lrow = lane & 15, lk = lane >> 4;
  const int row0 = blockIdx.x * 128;
  const int wrow = row0 + wave * 32;

  f32x4 acc[2][8];
  #pragma unroll
  for (int i = 0; i < 2; ++i)
    #pragma unroll
    for (int j = 0; j < 8; ++j) acc[i][j] = (f32x4){0.f, 0.f, 0.f, 0.f};

  #pragma unroll
  for (int kt = 0; kt < 4; ++kt) {
    bf16x8 a[2];
    #pragma unroll
    for (int rt = 0; rt < 2; ++rt) {
      int r = wrow + rt * 16 + lrow;
      bf16x8 av = (bf16x8){0, 0, 0, 0, 0, 0, 0, 0};
      if (r < M) {
        if (AF32) {
          const float* ap = (const float*)Av + (size_t)r * HD + kt * 32 + lk * 8;
          #pragma unroll
          for (int j = 0; j < 8; ++j) av[j] = (short)f2bf(ap[j]);
        } else {
          av = *(const bf16x8*)((const unsigned short*)Av + (size_t)r * HD + kt * 32 + lk * 8);
        }
      }
      a[rt] = av;
    }
    #pragma unroll
    for (int ct = 0; ct < 8; ++ct) {
      bf16x8 b = *(const bf16x8*)(Wt + (size_t)(ct * 16 + lrow) * HD + kt * 32 + lk * 8);
      acc[0][ct] = __builtin_amdgcn_mfma_f32_16x16x32_bf16(a[0], b, acc[0][ct], 0, 0, 0);
      acc[1][ct] = __builtin_amdgcn_mfma_f32_16x16x32_bf16(a[1], b, acc[1][ct], 0, 0, 0);
    }
  }

  #pragma unroll
  for (int rt = 0; rt < 2; ++rt)
    #pragma unroll
    for (int ct = 0; ct < 8; ++ct)
      #pragma unroll
      for (int reg = 0; reg < 4; ++reg) {
        int lr = wave * 32 + rt * 16 + lk * 4 + reg;
        Cs[lr][ct * 16 + lrow] = f2fp8(acc[rt][ct][reg]);
      }
  __syncthreads();

  #pragma unroll
  for (int i = 0; i < 8; ++i) {
    int idx = t + i * 256;       // 0..2047 uchar8 chunks
    int r = idx >> 4;
    int c = (idx & 15) * 8;
    int gr = row0 + r;
    if (gr < M)
      *(ucharv8*)(C + (size_t)gr * HD + c) = *(const ucharv8*)&Cs[r][c];
  }
}

// ---------------- pull aggregation, 8 lanes/node x 16B/lane, unroll-4 ----------------
// POOL=false: write bf16 rows. POOL=true: fused mean-pool partial (LDS run-reduce
// over sorted batch, one atomic row-add per run) — h2 never materialized.
template <bool IND, bool POOL>
__global__ __launch_bounds__(256) void k_agg8(const unsigned char* __restrict__ xw,
                                              const int* __restrict__ xidx,
                                              const int* __restrict__ rowptr,
                                              const uint2* __restrict__ csr,
                                              const float* __restrict__ dinv,
                                              const float* __restrict__ bias,
                                              unsigned short* __restrict__ outp,
                                              const int* __restrict__ batch,
                                              float* __restrict__ sums) {
  int t = threadIdx.x;
  int n = blockIdx.x * 32 + (t >> 3);   // grid exact: 3125*32 = NN
  int lane = t & 7;                     // cols [lane*16, lane*16+16)
  int beg = rowptr[n], end = rowptr[n + 1];

  int sn = IND ? xidx[n] : n;
  uint4 uself = *(const uint4*)(xw + (size_t)sn * HD + lane * 16);

  float acc[16];
  #pragma unroll
  for (int j = 0; j < 16; ++j) acc[j] = 0.f;

  int e = beg;
  for (; e + 3 < end; e += 4) {
    uint2 p0 = csr[e],     p1 = csr[e + 1];
    uint2 p2 = csr[e + 2], p3 = csr[e + 3];
    int s0 = (int)p0.x, s1 = (int)p1.x, s2 = (int)p2.x, s3 = (int)p3.x;
    if (IND) { s0 = xidx[s0]; s1 = xidx[s1]; s2 = xidx[s2]; s3 = xidx[s3]; }
    float c0 = __uint_as_float(p0.y), c1 = __uint_as_float(p1.y);
    float c2 = __uint_as_float(p2.y), c3 = __uint_as_float(p3.y);
    uint4 u0 = *(const uint4*)(xw + (size_t)s0 * HD + lane * 16);
    uint4 u1 = *(const uint4*)(xw + (size_t)s1 * HD + lane * 16);
    uint4 u2 = *(const uint4*)(xw + (size_t)s2 * HD + lane * 16);
    uint4 u3 = *(const uint4*)(xw + (size_t)s3 * HD + lane * 16);
    acc16(acc, u0, c0); acc16(acc, u1, c1);
    acc16(acc, u2, c2); acc16(acc, u3, c3);
  }
  for (; e < end; ++e) {
    uint2 p0 = csr[e];
    int s0 = (int)p0.x;
    float c0 = __uint_as_float(p0.y);
    if (IND) s0 = xidx[s0];
    uint4 u0 = *(const uint4*)(xw + (size_t)s0 * HD + lane * 16);
    acc16(acc, u0, c0);
  }

  float d = dinv[n];
  acc16(acc, uself, d * d);

  const float4* bp = reinterpret_cast<const float4*>(bias + lane * 16);
  float4 b0 = bp[0], b1 = bp[1], b2 = bp[2], b3 = bp[3];
  float o[16];
  o[0]  = fmaxf(acc[0]  + b0.x, 0.f); o[1]  = fmaxf(acc[1]  + b0.y, 0.f);
  o[2]  = fmaxf(acc[2]  + b0.z, 0.f); o[3]  = fmaxf(acc[3]  + b0.w, 0.f);
  o[4]  = fmaxf(acc[4]  + b1.x, 0.f); o[5]  = fmaxf(acc[5]  + b1.y, 0.f);
  o[6]  = fmaxf(acc[6]  + b1.z, 0.f); o[7]  = fmaxf(acc[7]  + b1.w, 0.f);
  o[8]  = fmaxf(acc[8]  + b2.x, 0.f); o[9]  = fmaxf(acc[9]  + b2.y, 0.f);
  o[10] = fmaxf(acc[10] + b2.z, 0.f); o[11] = fmaxf(acc[11] + b2.w, 0.f);
  o[12] = fmaxf(acc[12] + b3.x, 0.f); o[13] = fmaxf(acc[13] + b3.y, 0.f);
  o[14] = fmaxf(acc[14] + b3.z, 0.f); o[15] = fmaxf(acc[15] + b3.w, 0.f);

  if constexpr (!POOL) {
    ushortv8 r0, r1;
    #pragma unroll
    for (int j = 0; j < 8; ++j) { r0[j] = f2bf(o[j]); r1[j] = f2bf(o[8 + j]); }
    *(ushortv8*)(outp + (size_t)n * HD + lane * 16) = r0;
    *(ushortv8*)(outp + (size_t)n * HD + lane * 16 + 8) = r1;
  } else {
    __shared__ float pool[32][129];
    __shared__ int ib[32];
    int nl = t >> 3;
    #pragma unroll
    for (int j = 0; j < 16; ++j) pool[nl][lane * 16 + j] = o[j];
    if (t < 32) ib[t] = batch[blockIdx.x * 32 + t];
    __syncthreads();
    if (t < 128) {
      float a = 0.f;
      int c = t;
      #pragma unroll 4
      for (int i = 0; i < 32; ++i) {
        a += pool[i][c];
        if (i == 31 || ib[i + 1] != ib[i]) {
          atomicAdd(&sums[(size_t)ib[i] * HD + c], a);
          a = 0.f;
        }
      }
    }
  }
}

// ---------------- zero sums + counts ----------------
__global__ __launch_bounds__(256) void k_zero_counts(float* __restrict__ sums,
                                                     const int* __restrict__ batch,
                                                     float* __restrict__ cnt) {
  int i = blockIdx.x * blockDim.x + threadIdx.x;
  if (i < NB * HD) sums[i] = 0.f;
  if (blockIdx.x == 0 && threadIdx.x < NB) {
    int b = threadIdx.x;
    auto lb = [&](int v) {
      int lo = 0, hi = NN;
      while (lo < hi) { int m = (lo + hi) >> 1; if (batch[m] < v) lo = m + 1; else hi = m; }
      return lo;
    };
    cnt[b] = (float)(lb(b + 1) - lb(b));
  }
}

// ---------------- MLP head + softmax ----------------
__global__ __launch_bounds__(64) void k_head(const float* __restrict__ sums,
                                             const float* __restrict__ cnt,
                                             const float* __restrict__ W1,
                                             const float* __restrict__ b1,
                                             const float* __restrict__ W2,
                                             const float* __restrict__ b2,
                                             float* __restrict__ out) {
  int g = blockIdx.x, t = threadIdx.x;  // 64 threads
  __shared__ float gv[128];
  __shared__ float h[64];
  __shared__ float logits[2];
  float c = fmaxf(cnt[g], 1.0f);
  gv[t] = sums[g * HD + t] / c;
  gv[t + 64] = sums[g * HD + 64 + t] / c;
  __syncthreads();
  float acc = b1[t];
  for (int k = 0; k < 128; ++k) acc += gv[k] * W1[k * 64 + t];
  h[t] = fmaxf(acc, 0.f);
  __syncthreads();
  if (t < 2) {
    float a = b2[t];
    for (int j = 0; j < 64; ++j) a += h[j] * W2[j * 2 + t];
    logits[t] = a;
  }
  __syncthreads();
  if (t < 2) {
    float m = fmaxf(logits[0], logits[1]);
    float e0 = __expf(logits[0] - m), e1 = __expf(logits[1] - m);
    out[g * 2 + t] = (t == 0 ? e0 : e1) / (e0 + e1);
  }
}

// ---------------- launch ----------------
extern "C" void kernel_launch(void* const* d_in, const int* in_sizes, int n_in,
                              void* d_out, int out_size, void* d_ws, size_t ws_size,
                              hipStream_t stream) {
  const int*   x_idx = (const int*)d_in[0];
  const int*   eidx  = (const int*)d_in[1];
  const float* ew    = (const float*)d_in[2];
  const int*   batch = (const int*)d_in[3];
  const float* emb   = (const float*)d_in[4];
  const float* W1    = (const float*)d_in[5];
  const float* b1    = (const float*)d_in[6];
  const float* W2    = (const float*)d_in[7];
  const float* b2    = (const float*)d_in[8];
  const float* mW1   = (const float*)d_in[9];
  const float* mb1   = (const float*)d_in[10];
  const float* mW2   = (const float*)d_in[11];
  const float* mb2   = (const float*)d_in[12];
  const int* src = eidx;
  const int* dst = eidx + NE;
  float* out = (float*)d_out;

  char* ws = (char*)d_ws;
  size_t off = 0;
  auto alloc = [&](size_t bytes) {
    void* p = ws + off;
    off += (bytes + 255) & ~(size_t)255;
    return p;
  };
  int*   cntmat     = (int*)alloc((size_t)EBLK * NBUCK * 4);
  int*   totals     = (int*)alloc((size_t)NBUCK * 4);
  int*   bucketBase = (int*)alloc((size_t)(NBUCK + 1) * 4);
  int*   rowptr     = (int*)alloc((size_t)(NN + 1) * 4);
  float* dinv       = (float*)alloc((size_t)NN * 4);
  uint2* csr        = (uint2*)alloc((size_t)NE * 8);
  unsigned short* Wt1  = (unsigned short*)alloc((size_t)HD * HD * 2);
  unsigned short* Wt2  = (unsigned short*)alloc((size_t)HD * HD * 2);
  unsigned char* embW  = (unsigned char*)alloc((size_t)NV * HD);        // fp8
  unsigned char* bufA  = (unsigned char*)alloc((size_t)NN * HD);        // fp8
  float* sums    = (float*)alloc((size_t)NB * HD * 4);
  float* cnt     = (float*)alloc((size_t)NB * 4);
  // union region: bucket-sorted edge arrays (spair 12.8MB + dloc 1.6MB) live
  // only until k_bfill; bufB (bf16 h1) is first written by k_agg8<true> after.
  char* unionReg = (char*)alloc((size_t)NN * HD * 2);   // 25.6 MB
  uint2* spair = (uint2*)unionReg;
  unsigned char* dloc = (unsigned char*)(unionReg + (size_t)NE * 8);
  unsigned short* bufB = (unsigned short*)unionReg;

  // ---- CSR build via bucketed counting sort (zero global atomics) ----
  k_bcount<<<EBLK, 256, 0, stream>>>(dst, cntmat);
  k_cscan<<<NBUCK, 256, 0, stream>>>(cntmat, totals);
  k_tscan<<<1, 512, 0, stream>>>(totals, bucketBase);
  k_bscatter<<<EBLK, 256, 0, stream>>>(src, dst, ew, cntmat, bucketBase, dloc, spair);
  k_bdeg<<<NBUCK, 256, 0, stream>>>(dloc, spair, bucketBase, rowptr, dinv);
  k_bfill<<<NBUCK, 256, 0, stream>>>(dloc, spair, bucketBase, rowptr, dinv, csr);

  // weight prep (transpose + bf16, both weights in one launch)
  k_wprep2<<<128, 256, 0, stream>>>(W1, W2, Wt1, Wt2);

  // embW = fp8(emb_table @ W1)
  k_gemm_mfma<true><<<(NV + 127) / 128, 256, 0, stream>>>(emb, Wt1, embW, NV);

  // zero sums + counts (before fused-pool agg)
  k_zero_counts<<<64, 256, 0, stream>>>(sums, batch, cnt);

  // conv1: bufB = bf16(relu(agg(embW[xidx]) + b1))
  k_agg8<true, false><<<NN / 32, 256, 0, stream>>>(
      embW, x_idx, rowptr, csr, dinv, b1, bufB, nullptr, nullptr);

  // conv2: bufA = fp8(h1 @ W2) ; fused agg+mean-pool partials into sums
  k_gemm_mfma<false><<<(NN + 127) / 128, 256, 0, stream>>>(bufB, Wt2, bufA, NN);
  k_agg8<false, true><<<NN / 32, 256, 0, stream>>>(
      bufA, nullptr, rowptr, csr, dinv, b2, nullptr, batch, sums);

  // head
  k_head<<<NB, 64, 0, stream>>>(sums, cnt, mW1, mb1, mW2, mb2, out);
}